// Round 2
// baseline (93727.289 us; speedup 1.0000x reference)
//
#include <hip/hip_runtime.h>
#include <stdint.h>
#include <stddef.h>

#define BB 32
#define TT 64
#define DD 512
#define HH 8
#define HDIM 64
#define LL 4
#define FFD 2048
#define VV 128

#define NBLK 256
#define NTHR 512

// ---------------- threefry2x32 (20 rounds), matches JAX ----------------
__host__ __device__ inline uint32_t rotl32(uint32_t v, int n){ return (v << n) | (v >> (32 - n)); }

__host__ __device__ inline void tf2x32(uint32_t k0, uint32_t k1, uint32_t x0, uint32_t x1,
                                       uint32_t* o0, uint32_t* o1){
  uint32_t ks2 = k0 ^ k1 ^ 0x1BD11BDAu;
  x0 += k0; x1 += k1;
  x0 += x1; x1 = rotl32(x1,13); x1 ^= x0;
  x0 += x1; x1 = rotl32(x1,15); x1 ^= x0;
  x0 += x1; x1 = rotl32(x1,26); x1 ^= x0;
  x0 += x1; x1 = rotl32(x1, 6); x1 ^= x0;
  x0 += k1; x1 += ks2 + 1u;
  x0 += x1; x1 = rotl32(x1,17); x1 ^= x0;
  x0 += x1; x1 = rotl32(x1,29); x1 ^= x0;
  x0 += x1; x1 = rotl32(x1,16); x1 ^= x0;
  x0 += x1; x1 = rotl32(x1,24); x1 ^= x0;
  x0 += ks2; x1 += k0 + 2u;
  x0 += x1; x1 = rotl32(x1,13); x1 ^= x0;
  x0 += x1; x1 = rotl32(x1,15); x1 ^= x0;
  x0 += x1; x1 = rotl32(x1,26); x1 ^= x0;
  x0 += x1; x1 = rotl32(x1, 6); x1 ^= x0;
  x0 += k0; x1 += k1 + 3u;
  x0 += x1; x1 = rotl32(x1,17); x1 ^= x0;
  x0 += x1; x1 = rotl32(x1,29); x1 ^= x0;
  x0 += x1; x1 = rotl32(x1,16); x1 ^= x0;
  x0 += x1; x1 = rotl32(x1,24); x1 ^= x0;
  x0 += k1; x1 += ks2 + 4u;
  x0 += x1; x1 = rotl32(x1,13); x1 ^= x0;
  x0 += x1; x1 = rotl32(x1,15); x1 ^= x0;
  x0 += x1; x1 = rotl32(x1,26); x1 ^= x0;
  x0 += x1; x1 = rotl32(x1, 6); x1 ^= x0;
  x0 += ks2; x1 += k0 + 5u;
  *o0 = x0; *o1 = x1;
}

// ---------------- helpers ----------------
__device__ inline float dot_f4(const float* __restrict__ a, const float* __restrict__ w, int K){
  float acc = 0.f;
  const float4* a4 = (const float4*)a;
  const float4* w4 = (const float4*)w;
  int K4 = K >> 2;
  for (int k = 0; k < K4; ++k){
    float4 av = a4[k], wv = w4[k];
    acc = fmaf(av.x, wv.x, acc);
    acc = fmaf(av.y, wv.y, acc);
    acc = fmaf(av.z, wv.z, acc);
    acc = fmaf(av.w, wv.w, acc);
  }
  return acc;
}

// LayerNorm across a 512-thread block (one value per thread). red = __shared__ float[8].
// Identical reduction order to the round-1 passing kernel.
__device__ inline float block_ln(float v, float g, float bb, float* red){
  __syncthreads();
  float s = v;
  #pragma unroll
  for (int off = 32; off; off >>= 1) s += __shfl_xor(s, off);
  if ((threadIdx.x & 63) == 0) red[threadIdx.x >> 6] = s;
  __syncthreads();
  float mu = (red[0]+red[1]+red[2]+red[3]+red[4]+red[5]+red[6]+red[7]) * (1.0f/512.0f);
  float dv = v - mu;
  float sq = dv * dv;
  #pragma unroll
  for (int off = 32; off; off >>= 1) sq += __shfl_xor(sq, off);
  __syncthreads();
  if ((threadIdx.x & 63) == 0) red[threadIdx.x >> 6] = sq;
  __syncthreads();
  float var = (red[0]+red[1]+red[2]+red[3]+red[4]+red[5]+red[6]+red[7]) * (1.0f/512.0f);
  return dv * (1.0f / sqrtf(var + 1e-5f)) * g + bb;
}

// ---------------- hierarchical grid barrier ----------------
// bar layout (uints): sub[c] at [c*16] (c in 0..31), root at [512], gen at [520]
__device__ __forceinline__ void gbar(unsigned* bar){
  __syncthreads();
  if (threadIdx.x == 0){
    __threadfence();
    unsigned g = __hip_atomic_load(bar + 520, __ATOMIC_RELAXED, __HIP_MEMORY_SCOPE_AGENT);
    unsigned c = blockIdx.x & 31;  // 8 members: bid = c, c+32, ... (same XCD under %8 round-robin)
    bool release = false;
    if (__hip_atomic_fetch_add(bar + c*16, 1u, __ATOMIC_ACQ_REL, __HIP_MEMORY_SCOPE_AGENT) == 7u){
      if (__hip_atomic_fetch_add(bar + 512, 1u, __ATOMIC_ACQ_REL, __HIP_MEMORY_SCOPE_AGENT) == 31u){
        #pragma unroll
        for (int i = 0; i < 32; ++i)
          __hip_atomic_store(bar + i*16, 0u, __ATOMIC_RELAXED, __HIP_MEMORY_SCOPE_AGENT);
        __hip_atomic_store(bar + 512, 0u, __ATOMIC_RELAXED, __HIP_MEMORY_SCOPE_AGENT);
        __hip_atomic_fetch_add(bar + 520, 1u, __ATOMIC_RELEASE, __HIP_MEMORY_SCOPE_AGENT);
        release = true;
      }
    }
    if (!release){
      while (__hip_atomic_load(bar + 520, __ATOMIC_ACQUIRE, __HIP_MEMORY_SCOPE_AGENT) == g)
        __builtin_amdgcn_s_sleep(1);
    }
    __threadfence();
  }
  __syncthreads();
}

// ---------------- setup kernels ----------------
__global__ void k_tables(float* __restrict__ cosb, float* __restrict__ sinb){
  int tid = blockIdx.x * blockDim.x + threadIdx.x;  // TT*256
  int p = tid >> 8, i = tid & 255;
  float sv = (2.0f * (float)i + 204.8f) / 716.8f;
  float scale = powf(sv, (float)p / 16.0f);
  float invf = 1.0f / powf(10000.0f, (float)i / 256.0f);
  float ang = (float)p * invf;
  cosb[tid] = cosf(ang) * scale;
  sinb[tid] = sinf(ang) * scale;
}

__global__ void k_ca1(const float* __restrict__ mol, const float* __restrict__ w,
                      const float* __restrict__ bias, float* __restrict__ tmp){
  int tid = blockIdx.x * blockDim.x + threadIdx.x;  // LL*BB*DD
  int l = tid >> 14; int r = tid & 16383; int b = r >> 9; int d = r & 511;
  const float* wr = w + (size_t)l*3*DD*DD + (size_t)(2*DD + d)*DD;
  tmp[tid] = bias[l*3*DD + 2*DD + d] + dot_f4(mol + (size_t)b*DD, wr, DD);
}

__global__ void k_ca2(const float* __restrict__ tmp, const float* __restrict__ w,
                      const float* __restrict__ bias, float* __restrict__ cac){
  int tid = blockIdx.x * blockDim.x + threadIdx.x;  // LL*BB*DD
  int l = tid >> 14; int r = tid & 16383; int b = r >> 9; int d = r & 511;
  const float* wr = w + (size_t)l*DD*DD + (size_t)d*DD;
  cac[tid] = bias[l*DD + d] + dot_f4(tmp + ((size_t)l*BB + b)*DD, wr, DD);
}

__global__ void k_binit(unsigned* __restrict__ bar, int* __restrict__ pred){
  int tid = threadIdx.x;            // 1024 threads
  bar[tid] = 0u;
  pred[tid]        = ((tid & (TT-1)) == 0) ? 1 : 0;
  pred[tid + 1024] = (((tid + 1024) & (TT-1)) == 0) ? 1 : 0;
}

// ---------------- persistent decode kernel ----------------
struct KParams {
  const float *emb, *saw, *sab, *sow, *sob;
  const float *f1w, *f1b, *f2w, *f2b;
  const float *g1,*b1,*g2,*b2,*g3,*b3,*fg,*fb;
  const float *o1w,*o1b,*o2w,*o2b,*o3w,*o3b;
  const float *cosb,*sinb,*cac;
  float *kc,*vc,*x,*qb,*at,*ao,*h1,*fo,*xf,*hh1,*hh2;
  int *pred;
  unsigned *bar;
};

__global__ __launch_bounds__(NTHR) void k_persist(KParams P){
  const int bid = blockIdx.x, tid = threadIdx.x;
  __shared__ float red[8];
  __shared__ int   redi[2];
  __shared__ __align__(16) float sh[1088];

  for (int t = 1; t < TT; ++t){
    const int pp = t - 1;

    // ---- embed: 16384 outputs, 64/block ----
    if (tid < 64){
      int out = bid*64 + tid;
      int b = out >> 9, d = out & 511;
      int tok = P.pred[b*TT + pp];
      int i = d >> 1;
      float c = P.cosb[pp*256 + i], s = P.sinb[pp*256 + i];
      float e0 = P.emb[(size_t)tok*DD + (d & ~1)];
      float e1 = P.emb[(size_t)tok*DD + (d | 1)];
      P.x[out] = (d & 1) ? fmaf(e1, c, e0*s) : fmaf(e0, c, -(e1*s));
    }
    gbar(P.bar);

    for (int l = 0; l < LL; ++l){
      // ---- qkv: 49152 outputs (n-major: 32 lanes share one weight row), 192/block ----
      if (tid < 192){
        int out = bid*192 + tid;
        int n = out >> 5, b = out & 31;
        const float* wr = P.saw + (size_t)l*3*DD*DD + (size_t)n*DD;
        float acc = P.sab[l*3*DD + n] + dot_f4(P.x + (size_t)b*DD, wr, DD);
        if (n < DD){
          P.qb[b*DD + n] = acc;
        } else if (n < 2*DD){
          int h = (n - DD) >> 6, hd = (n - DD) & 63;
          P.kc[((((size_t)l*BB + b)*HH + h)*TT + pp)*HDIM + hd] = acc;
        } else {
          int h = (n - 2*DD) >> 6, hd = (n - 2*DD) & 63;
          P.vc[((((size_t)l*BB + b)*HH + h)*TT + pp)*HDIM + hd] = acc;
        }
      }
      gbar(P.bar);

      // ---- attn: block = (b,h), one wave ----
      {
        int b = bid >> 3, h = bid & 7;
        if (tid < 64) sh[tid] = P.qb[b*DD + h*HDIM + tid];
        __syncthreads();
        if (tid < 64){
          int lane = tid;
          float* qs = sh; float* ps = sh + 64;
          const float* kb = P.kc + (((size_t)l*BB + b)*HH + h)*TT*HDIM;
          float s = -INFINITY;
          if (lane <= pp && P.pred[b*TT + lane] != 0){
            const float* kr = kb + lane*HDIM;
            float acc = 0.f;
            #pragma unroll
            for (int k2 = 0; k2 < HDIM; ++k2) acc = fmaf(qs[k2], kr[k2], acc);
            s = acc * 0.125f;
          }
          float m = s;
          #pragma unroll
          for (int off = 32; off; off >>= 1) m = fmaxf(m, __shfl_xor(m, off));
          float e = (s == -INFINITY) ? 0.f : expf(s - m);
          float sum = e;
          #pragma unroll
          for (int off = 32; off; off >>= 1) sum += __shfl_xor(sum, off);
          ps[lane] = e / sum;
          const float* vb = P.vc + (((size_t)l*BB + b)*HH + h)*TT*HDIM;
          float o = 0.f;
          for (int j = 0; j <= pp; ++j) o = fmaf(ps[j], vb[j*HDIM + lane], o);
          P.at[b*DD + h*HDIM + lane] = o;
        }
      }
      gbar(P.bar);

      // ---- oproj: 16384 outputs, 64/block ----
      if (tid < 64){
        int out = bid*64 + tid;
        int d = out >> 5, b = out & 31;
        float a = P.sob[l*DD + d] + dot_f4(P.at + (size_t)b*DD, P.sow + ((size_t)l*DD + d)*DD, DD);
        P.ao[b*DD + d] = a;
      }
      gbar(P.bar);

      // ---- residual + ln1 + cross-attn const + ln2: 32 row blocks ----
      if (bid < 32){
        int b = bid, d = tid;
        float xv = P.x[b*DD + d] + P.ao[b*DD + d];
        xv = block_ln(xv, P.g1[l*DD + d], P.b1[l*DD + d], red);
        xv = xv + P.cac[((size_t)l*BB + b)*DD + d];
        xv = block_ln(xv, P.g2[l*DD + d], P.b2[l*DD + d], red);
        P.x[b*DD + d] = xv;
      }
      gbar(P.bar);

      // ---- ff1: 65536 outputs, 256/block ----
      if (tid < 256){
        int out = bid*256 + tid;
        int n = out >> 5, b = out & 31;
        float acc = P.f1b[l*FFD + n] + dot_f4(P.x + (size_t)b*DD, P.f1w + ((size_t)l*FFD + n)*DD, DD);
        P.h1[b*FFD + n] = acc / (1.0f + expf(-acc));
      }
      gbar(P.bar);

      // ---- ff2: 16384 outputs (full 2048-dot, order-identical), 64/block ----
      if (tid < 64){
        int out = bid*64 + tid;
        int d = out >> 5, b = out & 31;
        float f = P.f2b[l*DD + d] + dot_f4(P.h1 + (size_t)b*FFD, P.f2w + ((size_t)l*DD + d)*FFD, FFD);
        P.fo[b*DD + d] = f;
      }
      gbar(P.bar);

      // ---- residual + ln3 (+ final ln at last layer): 32 row blocks ----
      if (bid < 32){
        int b = bid, d = tid;
        float xv = P.x[b*DD + d] + P.fo[b*DD + d];
        xv = block_ln(xv, P.g3[l*DD + d], P.b3[l*DD + d], red);
        P.x[b*DD + d] = xv;
        if (l == LL-1){
          float o = block_ln(xv, P.fg[d], P.fb[d], red);
          P.xf[b*DD + d] = o;
        }
      }
      gbar(P.bar);
    }

    // ---- head1: 32768 outputs, 128/block ----
    if (tid < 128){
      int out = bid*128 + tid;
      int n = out >> 5, b = out & 31;
      float a = P.o1b[n] + dot_f4(P.xf + (size_t)b*DD, P.o1w + (size_t)n*DD, DD);
      P.hh1[b*1024 + n] = 0.5f * a * (1.0f + erff(a / 1.41421356237309504880f));
    }
    gbar(P.bar);

    // ---- head2: 32768 outputs, 128/block ----
    if (tid < 128){
      int out = bid*128 + tid;
      int n = out >> 5, b = out & 31;
      float a = P.o2b[n] + dot_f4(P.hh1 + (size_t)b*1024, P.o2w + (size_t)n*1024, 1024);
      P.hh2[b*1024 + n] = 0.5f * a * (1.0f + erff(a / 1.41421356237309504880f));
    }
    gbar(P.bar);

    // ---- sample: 32 row blocks ----
    if (bid < 32){
      int b = bid, v = tid;
      for (int k = tid; k < 1024; k += NTHR) sh[k] = P.hh2[b*1024 + k];
      __syncthreads();
      float sv = 0.f;
      if (tid < 128){
        float acc = P.o3b[v] + dot_f4(sh, P.o3w + (size_t)v*1024, 1024);
        sv = acc / 0.1f;
      }
      float m = (tid < 128) ? sv : -INFINITY;
      #pragma unroll
      for (int off = 32; off; off >>= 1) m = fmaxf(m, __shfl_xor(m, off));
      __syncthreads();
      if (tid < 128 && (tid & 63) == 0) red[tid >> 6] = m;
      __syncthreads();
      m = fmaxf(red[0], red[1]);
      float e = (tid < 128) ? expf(sv - m) : 0.f;
      float sum = e;
      #pragma unroll
      for (int off = 32; off; off >>= 1) sum += __shfl_xor(sum, off);
      __syncthreads();
      if (tid < 128 && (tid & 63) == 0) red[tid >> 6] = sum;
      __syncthreads();
      sum = red[0] + red[1];
      float bv = -INFINITY; int bi = 0x7fffffff;
      if (tid < 128){
        float lp = (sv - m) - logf(sum);
        uint32_t kk0, kk1, o0, o1;
        tf2x32(0u, 1u, 0u, (uint32_t)t, &kk0, &kk1);
        tf2x32(kk0, kk1, 0u, (uint32_t)(b*VV + v), &o0, &o1);
        uint32_t bits = o0 ^ o1;
        float u = __uint_as_float((bits >> 9) | 0x3F800000u) - 1.0f;
        float g = -logf(-logf(u + 1e-9f) + 1e-9f);
        bv = lp + g; bi = v;
      }
      #pragma unroll
      for (int off = 32; off; off >>= 1){
        float ov = __shfl_xor(bv, off);
        int   oi = __shfl_xor(bi, off);
        if (ov > bv || (ov == bv && oi < bi)){ bv = ov; bi = oi; }
      }
      __syncthreads();
      if (tid < 128 && (tid & 63) == 0){ red[tid >> 6] = bv; redi[tid >> 6] = bi; }
      __syncthreads();
      if (tid == 0){
        float v0 = red[0], v1 = red[1]; int i0 = redi[0], i1 = redi[1];
        P.pred[b*TT + t] = (v1 > v0 || (v1 == v0 && i1 < i0)) ? i1 : i0;
      }
    }
    gbar(P.bar);
  }
}

// ---------------- host ----------------
extern "C" void kernel_launch(void* const* d_in, const int* in_sizes, int n_in,
                              void* d_out, int out_size, void* d_ws, size_t ws_size,
                              hipStream_t stream){
  (void)in_sizes; (void)n_in; (void)out_size; (void)ws_size;
  const float* mol      = (const float*)d_in[1];
  KParams P;
  P.emb  = (const float*)d_in[2];
  P.saw  = (const float*)d_in[3];
  P.sab  = (const float*)d_in[4];
  P.sow  = (const float*)d_in[5];
  P.sob  = (const float*)d_in[6];
  const float* ca_in_w  = (const float*)d_in[7];
  const float* ca_in_b  = (const float*)d_in[8];
  const float* ca_out_w = (const float*)d_in[9];
  const float* ca_out_b = (const float*)d_in[10];
  P.f1w = (const float*)d_in[11];
  P.f1b = (const float*)d_in[12];
  P.f2w = (const float*)d_in[13];
  P.f2b = (const float*)d_in[14];
  P.g1  = (const float*)d_in[15];
  P.b1  = (const float*)d_in[16];
  P.g2  = (const float*)d_in[17];
  P.b2  = (const float*)d_in[18];
  P.g3  = (const float*)d_in[19];
  P.b3  = (const float*)d_in[20];
  P.fg  = (const float*)d_in[21];
  P.fb  = (const float*)d_in[22];
  P.o1w = (const float*)d_in[23];
  P.o1b = (const float*)d_in[24];
  P.o2w = (const float*)d_in[25];
  P.o2b = (const float*)d_in[26];
  P.o3w = (const float*)d_in[27];
  P.o3b = (const float*)d_in[28];

  unsigned* bar = (unsigned*)d_ws;          // 1024 uints
  float* ws = (float*)d_ws + 1024;
  float* cosb   = ws;                     // 16384
  float* sinb   = cosb + 16384;           // 16384
  float* ca_tmp = sinb + 16384;           // 65536
  float* cac    = ca_tmp + 65536;         // 65536
  float* kc     = cac + 65536;            // 4194304
  float* vc     = kc + 4194304;           // 4194304
  float* x      = vc + 4194304;           // 16384
  float* qb     = x + 16384;              // 16384
  float* at     = qb + 16384;             // 16384
  float* ao     = at + 16384;             // 16384
  float* h1     = ao + 16384;             // 65536
  float* fo     = h1 + 65536;             // 16384
  float* xf     = fo + 16384;             // 16384
  float* hh1    = xf + 16384;             // 32768
  float* hh2    = hh1 + 32768;            // 32768

  P.cosb = cosb; P.sinb = sinb; P.cac = cac;
  P.kc = kc; P.vc = vc; P.x = x; P.qb = qb; P.at = at; P.ao = ao;
  P.h1 = h1; P.fo = fo; P.xf = xf; P.hh1 = hh1; P.hh2 = hh2;
  P.pred = (int*)d_out;
  P.bar = bar;

  k_binit<<<1, 1024, 0, stream>>>(bar, P.pred);
  k_tables<<<64, 256, 0, stream>>>(cosb, sinb);
  k_ca1<<<256, 256, 0, stream>>>(mol, ca_in_w, ca_in_b, ca_tmp);
  k_ca2<<<256, 256, 0, stream>>>(ca_tmp, ca_out_w, ca_out_b, cac);
  k_persist<<<NBLK, NTHR, 0, stream>>>(P);
}

// Round 3
// 66342.004 us; speedup vs baseline: 1.4128x; 1.4128x over previous
//
#include <hip/hip_runtime.h>
#include <stdint.h>
#include <stddef.h>

#define BB 32
#define TT 64
#define DD 512
#define HH 8
#define HDIM 64
#define LL 4
#define FFD 2048
#define VV 128

#define NBLK 256
#define NTHR 512

// ---------------- threefry2x32 (20 rounds), matches JAX ----------------
__host__ __device__ inline uint32_t rotl32(uint32_t v, int n){ return (v << n) | (v >> (32 - n)); }

__host__ __device__ inline void tf2x32(uint32_t k0, uint32_t k1, uint32_t x0, uint32_t x1,
                                       uint32_t* o0, uint32_t* o1){
  uint32_t ks2 = k0 ^ k1 ^ 0x1BD11BDAu;
  x0 += k0; x1 += k1;
  x0 += x1; x1 = rotl32(x1,13); x1 ^= x0;
  x0 += x1; x1 = rotl32(x1,15); x1 ^= x0;
  x0 += x1; x1 = rotl32(x1,26); x1 ^= x0;
  x0 += x1; x1 = rotl32(x1, 6); x1 ^= x0;
  x0 += k1; x1 += ks2 + 1u;
  x0 += x1; x1 = rotl32(x1,17); x1 ^= x0;
  x0 += x1; x1 = rotl32(x1,29); x1 ^= x0;
  x0 += x1; x1 = rotl32(x1,16); x1 ^= x0;
  x0 += x1; x1 = rotl32(x1,24); x1 ^= x0;
  x0 += ks2; x1 += k0 + 2u;
  x0 += x1; x1 = rotl32(x1,13); x1 ^= x0;
  x0 += x1; x1 = rotl32(x1,15); x1 ^= x0;
  x0 += x1; x1 = rotl32(x1,26); x1 ^= x0;
  x0 += x1; x1 = rotl32(x1, 6); x1 ^= x0;
  x0 += k0; x1 += k1 + 3u;
  x0 += x1; x1 = rotl32(x1,17); x1 ^= x0;
  x0 += x1; x1 = rotl32(x1,29); x1 ^= x0;
  x0 += x1; x1 = rotl32(x1,16); x1 ^= x0;
  x0 += x1; x1 = rotl32(x1,24); x1 ^= x0;
  x0 += k1; x1 += ks2 + 4u;
  x0 += x1; x1 = rotl32(x1,13); x1 ^= x0;
  x0 += x1; x1 = rotl32(x1,15); x1 ^= x0;
  x0 += x1; x1 = rotl32(x1,26); x1 ^= x0;
  x0 += x1; x1 = rotl32(x1, 6); x1 ^= x0;
  x0 += ks2; x1 += k0 + 5u;
  *o0 = x0; *o1 = x1;
}

// ---------------- helpers ----------------
__device__ inline float dot_f4(const float* __restrict__ a, const float* __restrict__ w, int K){
  float acc = 0.f;
  const float4* a4 = (const float4*)a;
  const float4* w4 = (const float4*)w;
  int K4 = K >> 2;
  for (int k = 0; k < K4; ++k){
    float4 av = a4[k], wv = w4[k];
    acc = fmaf(av.x, wv.x, acc);
    acc = fmaf(av.y, wv.y, acc);
    acc = fmaf(av.z, wv.z, acc);
    acc = fmaf(av.w, wv.w, acc);
  }
  return acc;
}

// LayerNorm across a 512-thread block (one value per thread). Identical order to round-1.
__device__ inline float block_ln(float v, float g, float bb, float* red){
  __syncthreads();
  float s = v;
  #pragma unroll
  for (int off = 32; off; off >>= 1) s += __shfl_xor(s, off);
  if ((threadIdx.x & 63) == 0) red[threadIdx.x >> 6] = s;
  __syncthreads();
  float mu = (red[0]+red[1]+red[2]+red[3]+red[4]+red[5]+red[6]+red[7]) * (1.0f/512.0f);
  float dv = v - mu;
  float sq = dv * dv;
  #pragma unroll
  for (int off = 32; off; off >>= 1) sq += __shfl_xor(sq, off);
  __syncthreads();
  if ((threadIdx.x & 63) == 0) red[threadIdx.x >> 6] = sq;
  __syncthreads();
  float var = (red[0]+red[1]+red[2]+red[3]+red[4]+red[5]+red[6]+red[7]) * (1.0f/512.0f);
  return dv * (1.0f / sqrtf(var + 1e-5f)) * g + bb;
}

// ---------------- hierarchical grid barrier (relaxed spin; single fences) ----------------
// bar layout (uints): sub[c] at [c*16] (c in 0..31), root at [512], gen at [520]
__device__ __forceinline__ void gbar(unsigned* bar){
  __syncthreads();
  if (threadIdx.x == 0){
    __builtin_amdgcn_fence(__ATOMIC_RELEASE, "agent");   // write back my block's stores
    unsigned g = __hip_atomic_load(bar + 520, __ATOMIC_RELAXED, __HIP_MEMORY_SCOPE_AGENT);
    unsigned c = blockIdx.x & 31;
    bool release = false;
    if (__hip_atomic_fetch_add(bar + c*16, 1u, __ATOMIC_RELAXED, __HIP_MEMORY_SCOPE_AGENT) == 7u){
      if (__hip_atomic_fetch_add(bar + 512, 1u, __ATOMIC_RELAXED, __HIP_MEMORY_SCOPE_AGENT) == 31u){
        #pragma unroll
        for (int i = 0; i < 32; ++i)
          __hip_atomic_store(bar + i*16, 0u, __ATOMIC_RELAXED, __HIP_MEMORY_SCOPE_AGENT);
        __hip_atomic_store(bar + 512, 0u, __ATOMIC_RELAXED, __HIP_MEMORY_SCOPE_AGENT);
        // RELEASE: resets must be visible at coherence point before gen advances
        __hip_atomic_fetch_add(bar + 520, 1u, __ATOMIC_RELEASE, __HIP_MEMORY_SCOPE_AGENT);
        release = true;
      }
    }
    if (!release){
      while (__hip_atomic_load(bar + 520, __ATOMIC_RELAXED, __HIP_MEMORY_SCOPE_AGENT) == g)
        __builtin_amdgcn_s_sleep(2);
    }
    __builtin_amdgcn_fence(__ATOMIC_ACQUIRE, "agent");   // one invalidate per block per barrier
  }
  __syncthreads();
}

// ---------------- setup kernels ----------------
__global__ void k_tables(float* __restrict__ cosb, float* __restrict__ sinb){
  int tid = blockIdx.x * blockDim.x + threadIdx.x;  // TT*256
  int p = tid >> 8, i = tid & 255;
  float sv = (2.0f * (float)i + 204.8f) / 716.8f;
  float scale = powf(sv, (float)p / 16.0f);
  float invf = 1.0f / powf(10000.0f, (float)i / 256.0f);
  float ang = (float)p * invf;
  cosb[tid] = cosf(ang) * scale;
  sinb[tid] = sinf(ang) * scale;
}

__global__ void k_ca1(const float* __restrict__ mol, const float* __restrict__ w,
                      const float* __restrict__ bias, float* __restrict__ tmp){
  int tid = blockIdx.x * blockDim.x + threadIdx.x;  // LL*BB*DD
  int l = tid >> 14; int r = tid & 16383; int b = r >> 9; int d = r & 511;
  const float* wr = w + (size_t)l*3*DD*DD + (size_t)(2*DD + d)*DD;
  tmp[tid] = bias[l*3*DD + 2*DD + d] + dot_f4(mol + (size_t)b*DD, wr, DD);
}

__global__ void k_ca2(const float* __restrict__ tmp, const float* __restrict__ w,
                      const float* __restrict__ bias, float* __restrict__ cac){
  int tid = blockIdx.x * blockDim.x + threadIdx.x;  // LL*BB*DD
  int l = tid >> 14; int r = tid & 16383; int b = r >> 9; int d = r & 511;
  const float* wr = w + (size_t)l*DD*DD + (size_t)d*DD;
  cac[tid] = bias[l*DD + d] + dot_f4(tmp + ((size_t)l*BB + b)*DD, wr, DD);
}

__global__ void k_binit(unsigned* __restrict__ bar, int* __restrict__ pred){
  int tid = threadIdx.x;            // 1024 threads
  bar[tid] = 0u;
  pred[tid]        = ((tid & (TT-1)) == 0) ? 1 : 0;
  pred[tid + 1024] = (((tid + 1024) & (TT-1)) == 0) ? 1 : 0;
}

// tiled transpose: in [N][K] row-major (+z*N*K) -> out [K][N] (+z*K*N)
__global__ void k_transpose(const float* __restrict__ in, float* __restrict__ out, int N, int K){
  __shared__ float tile[32][33];
  size_t zo = (size_t)blockIdx.z * N * K;
  const float* inp = in + zo;
  float* outp = out + zo;
  int kt = blockIdx.x * 32, nt = blockIdx.y * 32;
  int tx = threadIdx.x & 31, ty = threadIdx.x >> 5;  // 256 thr: ty 0..7
  for (int r = ty; r < 32; r += 8) tile[r][tx] = inp[(size_t)(nt + r)*K + kt + tx];
  __syncthreads();
  for (int r = ty; r < 32; r += 8) outp[(size_t)(kt + r)*N + nt + tx] = tile[tx][r];
}

// ---------------- generic coalesced matmul accumulate ----------------
// WT: [KTOT][N] col-major-in-n. Lanes span 2 n-halves (n0, n0+64). BPW b-rows per wave.
// Per-output fmaf chain is k-ascending => bit-identical to sequential dot.
template<int KTOT, int KP, int BPW>
__device__ __forceinline__ void mm_acc(
    const float* __restrict__ WT, const int N,
    const float* __restrict__ src, const int sstride,
    const int b0, const int BPB, const int n0,
    float* __restrict__ stage, float acc[BPW][2])
{
  const int tid = threadIdx.x;
  const int bl = (tid >> 6) * BPW;
  #pragma unroll
  for (int b = 0; b < BPW; ++b){ acc[b][0] = 0.f; acc[b][1] = 0.f; }
  for (int kb = 0; kb < KTOT; kb += KP){
    __syncthreads();
    const int total = BPB * (KP/4);
    for (int i = tid; i < total; i += NTHR){
      int b = i / (KP/4), k4 = i - b*(KP/4);
      ((float4*)stage)[i] = *(const float4*)(src + (size_t)(b0 + b)*sstride + kb + k4*4);
    }
    __syncthreads();
    for (int kk = 0; kk < KP; kk += 16){
      float w0[16], w1[16];
      #pragma unroll
      for (int u = 0; u < 16; ++u){
        w0[u] = WT[(size_t)(kb + kk + u)*N + n0];
        w1[u] = WT[(size_t)(kb + kk + u)*N + n0 + 64];
      }
      #pragma unroll
      for (int b = 0; b < BPW; ++b){
        const float4* xr = (const float4*)(stage + (size_t)(bl + b)*KP + kk);
        float xv[16];
        *(float4*)(xv+0)  = xr[0];
        *(float4*)(xv+4)  = xr[1];
        *(float4*)(xv+8)  = xr[2];
        *(float4*)(xv+12) = xr[3];
        #pragma unroll
        for (int u = 0; u < 16; ++u){
          acc[b][0] = fmaf(xv[u], w0[u], acc[b][0]);
          acc[b][1] = fmaf(xv[u], w1[u], acc[b][1]);
        }
      }
    }
  }
}

// ---------------- persistent decode kernel ----------------
struct KParams {
  const float *emb, *sab, *sob, *f1b, *f2b;
  const float *g1,*b1,*g2,*b2,*g3,*b3,*fg,*fb;
  const float *o1b,*o2b,*o3w,*o3b;
  const float *cosb,*sinb,*cac;
  const float *sawT,*sowT,*f1wT,*f2wT,*o1wT,*o2wT;   // transposed weights [K][N]
  float *kc,*vc,*x,*qb,*at,*ao,*h1,*fo,*xf,*hh1,*hh2;
  int *pred;
  unsigned *bar;
};

__global__ __launch_bounds__(NTHR) void k_persist(KParams P){
  const int bid = blockIdx.x, tid = threadIdx.x;
  const int lane = tid & 63;
  __shared__ __align__(16) float stage[16384];   // 64 KB, aliased below
  float* red  = stage + 16376;                   // 8 floats
  int*   redi = (int*)(stage + 16372);           // 2 ints

  for (int t = 1; t < TT; ++t){
    const int pp = t - 1;

    // ---- embed: 16384 outputs, 64/block ----
    if (tid < 64){
      int out = bid*64 + tid;
      int b = out >> 9, d = out & 511;
      int tok = P.pred[b*TT + pp];
      int i = d >> 1;
      float c = P.cosb[pp*256 + i], s = P.sinb[pp*256 + i];
      float e0 = P.emb[(size_t)tok*DD + (d & ~1)];
      float e1 = P.emb[(size_t)tok*DD + (d | 1)];
      P.x[out] = (d & 1) ? fmaf(e1, c, e0*s) : fmaf(e0, c, -(e1*s));
    }
    gbar(P.bar);

    for (int l = 0; l < LL; ++l){
      // ---- qkv: N=1536, 12 blocks, BPB=32, BPW=4 ----
      if (bid < 12){
        const int nsl = bid, n0 = nsl*128 + lane;
        float acc[4][2];
        mm_acc<512,512,4>(P.sawT + (size_t)l*512*1536, 1536, P.x, 512, 0, 32, n0, stage, acc);
        const int bl = (tid >> 6) * 4;
        #pragma unroll
        for (int b = 0; b < 4; ++b){
          #pragma unroll
          for (int hf = 0; hf < 2; ++hf){
            int n = n0 + hf*64;
            int bb2 = bl + b;
            float v = P.sab[l*3*DD + n] + acc[b][hf];
            if (n < DD){
              P.qb[bb2*DD + n] = v;
            } else if (n < 2*DD){
              int h = (n - DD) >> 6, hd = (n - DD) & 63;
              P.kc[((((size_t)l*BB + bb2)*HH + h)*TT + pp)*HDIM + hd] = v;
            } else {
              int h = (n - 2*DD) >> 6, hd = (n - 2*DD) & 63;
              P.vc[((((size_t)l*BB + bb2)*HH + h)*TT + pp)*HDIM + hd] = v;
            }
          }
        }
      }
      gbar(P.bar);

      // ---- attn: block = (b,h), one wave; exact round-2 math ----
      {
        int b = bid >> 3, h = bid & 7;
        if (tid < 64) stage[tid] = P.qb[b*DD + h*HDIM + tid];
        __syncthreads();
        if (tid < 64){
          float* qs = stage; float* ps = stage + 64;
          const float* kb = P.kc + (((size_t)l*BB + b)*HH + h)*TT*HDIM;
          float s = -INFINITY;
          if (lane <= pp && P.pred[b*TT + lane] != 0){
            const float* kr = kb + lane*HDIM;
            float acc = 0.f;
            #pragma unroll
            for (int k2 = 0; k2 < HDIM; ++k2) acc = fmaf(qs[k2], kr[k2], acc);
            s = acc * 0.125f;
          }
          float m = s;
          #pragma unroll
          for (int off = 32; off; off >>= 1) m = fmaxf(m, __shfl_xor(m, off));
          float e = (s == -INFINITY) ? 0.f : expf(s - m);
          float sum = e;
          #pragma unroll
          for (int off = 32; off; off >>= 1) sum += __shfl_xor(sum, off);
          ps[lane] = e / sum;
          const float* vb = P.vc + (((size_t)l*BB + b)*HH + h)*TT*HDIM;
          float o = 0.f;
          int j = 0;
          for (; j + 8 <= t; j += 8){            // t = pp+1 keys; order-preserving batched loads
            float vv[8];
            #pragma unroll
            for (int u = 0; u < 8; ++u) vv[u] = vb[(j+u)*HDIM + lane];
            #pragma unroll
            for (int u = 0; u < 8; ++u) o = fmaf(ps[j+u], vv[u], o);
          }
          for (; j <= pp; ++j) o = fmaf(ps[j], vb[j*HDIM + lane], o);
          P.at[b*DD + h*HDIM + lane] = o;
        }
      }
      gbar(P.bar);

      // ---- oproj: N=512, 8 blocks, BPB=16, BPW=2 ----
      if (bid < 8){
        const int nsl = bid >> 1, b0 = (bid & 1)*16, n0 = nsl*128 + lane;
        float acc[2][2];
        mm_acc<512,512,2>(P.sowT + (size_t)l*512*512, 512, P.at, 512, b0, 16, n0, stage, acc);
        const int bl = (tid >> 6) * 2;
        #pragma unroll
        for (int b = 0; b < 2; ++b)
          #pragma unroll
          for (int hf = 0; hf < 2; ++hf){
            int n = n0 + hf*64;
            P.ao[(size_t)(b0 + bl + b)*DD + n] = P.sob[l*DD + n] + acc[b][hf];
          }
      }
      gbar(P.bar);

      // ---- residual + ln1 + cross-attn const + ln2: 32 row blocks ----
      if (bid < 32){
        int b = bid, d = tid;
        float xv = P.x[b*DD + d] + P.ao[b*DD + d];
        xv = block_ln(xv, P.g1[l*DD + d], P.b1[l*DD + d], red);
        xv = xv + P.cac[((size_t)l*BB + b)*DD + d];
        xv = block_ln(xv, P.g2[l*DD + d], P.b2[l*DD + d], red);
        P.x[b*DD + d] = xv;
      }
      gbar(P.bar);

      // ---- ff1: N=2048, 16 blocks, BPB=32, BPW=4, silu ----
      if (bid < 16){
        const int nsl = bid, n0 = nsl*128 + lane;
        float acc[4][2];
        mm_acc<512,512,4>(P.f1wT + (size_t)l*512*2048, 2048, P.x, 512, 0, 32, n0, stage, acc);
        const int bl = (tid >> 6) * 4;
        #pragma unroll
        for (int b = 0; b < 4; ++b)
          #pragma unroll
          for (int hf = 0; hf < 2; ++hf){
            int n = n0 + hf*64;
            float v = P.f1b[l*FFD + n] + acc[b][hf];
            P.h1[(size_t)(bl + b)*FFD + n] = v / (1.0f + expf(-v));
          }
      }
      gbar(P.bar);

      // ---- ff2: N=512, K=2048 (2 LDS phases), 8 blocks, BPB=16, BPW=2 ----
      if (bid < 8){
        const int nsl = bid >> 1, b0 = (bid & 1)*16, n0 = nsl*128 + lane;
        float acc[2][2];
        mm_acc<2048,1024,2>(P.f2wT + (size_t)l*2048*512, 512, P.h1, 2048, b0, 16, n0, stage, acc);
        const int bl = (tid >> 6) * 2;
        #pragma unroll
        for (int b = 0; b < 2; ++b)
          #pragma unroll
          for (int hf = 0; hf < 2; ++hf){
            int n = n0 + hf*64;
            P.fo[(size_t)(b0 + bl + b)*DD + n] = P.f2b[l*DD + n] + acc[b][hf];
          }
      }
      gbar(P.bar);

      // ---- residual + ln3 (+ final ln at last layer): 32 row blocks ----
      if (bid < 32){
        int b = bid, d = tid;
        float xv = P.x[b*DD + d] + P.fo[b*DD + d];
        xv = block_ln(xv, P.g3[l*DD + d], P.b3[l*DD + d], red);
        P.x[b*DD + d] = xv;
        if (l == LL-1){
          float o = block_ln(xv, P.fg[d], P.fb[d], red);
          P.xf[b*DD + d] = o;
        }
      }
      gbar(P.bar);
    }

    // ---- head1: N=1024, K=512, 16 blocks, BPB=16, BPW=2, gelu ----
    if (bid < 16){
      const int nsl = bid >> 1, b0 = (bid & 1)*16, n0 = nsl*128 + lane;
      float acc[2][2];
      mm_acc<512,512,2>(P.o1wT, 1024, P.xf, 512, b0, 16, n0, stage, acc);
      const int bl = (tid >> 6) * 2;
      #pragma unroll
      for (int b = 0; b < 2; ++b)
        #pragma unroll
        for (int hf = 0; hf < 2; ++hf){
          int n = n0 + hf*64;
          float a = P.o1b[n] + acc[b][hf];
          P.hh1[(size_t)(b0 + bl + b)*1024 + n] = 0.5f * a * (1.0f + erff(a / 1.41421356237309504880f));
        }
    }
    gbar(P.bar);

    // ---- head2: N=1024, K=1024, 16 blocks, BPB=16, BPW=2, gelu ----
    if (bid < 16){
      const int nsl = bid >> 1, b0 = (bid & 1)*16, n0 = nsl*128 + lane;
      float acc[2][2];
      mm_acc<1024,1024,2>(P.o2wT, 1024, P.hh1, 1024, b0, 16, n0, stage, acc);
      const int bl = (tid >> 6) * 2;
      #pragma unroll
      for (int b = 0; b < 2; ++b)
        #pragma unroll
        for (int hf = 0; hf < 2; ++hf){
          int n = n0 + hf*64;
          float a = P.o2b[n] + acc[b][hf];
          P.hh2[(size_t)(b0 + bl + b)*1024 + n] = 0.5f * a * (1.0f + erff(a / 1.41421356237309504880f));
        }
    }
    gbar(P.bar);

    // ---- sample: 32 row blocks (identical to round-2) ----
    if (bid < 32){
      int b = bid, v = tid;
      for (int k = tid; k < 1024; k += NTHR) stage[k] = P.hh2[b*1024 + k];
      __syncthreads();
      float sv = 0.f;
      if (tid < 128){
        float acc = P.o3b[v] + dot_f4(stage, P.o3w + (size_t)v*1024, 1024);
        sv = acc / 0.1f;
      }
      float m = (tid < 128) ? sv : -INFINITY;
      #pragma unroll
      for (int off = 32; off; off >>= 1) m = fmaxf(m, __shfl_xor(m, off));
      __syncthreads();
      if (tid < 128 && (tid & 63) == 0) red[tid >> 6] = m;
      __syncthreads();
      m = fmaxf(red[0], red[1]);
      float e = (tid < 128) ? expf(sv - m) : 0.f;
      float sum = e;
      #pragma unroll
      for (int off = 32; off; off >>= 1) sum += __shfl_xor(sum, off);
      __syncthreads();
      if (tid < 128 && (tid & 63) == 0) red[tid >> 6] = sum;
      __syncthreads();
      sum = red[0] + red[1];
      float bv = -INFINITY; int bi = 0x7fffffff;
      if (tid < 128){
        float lp = (sv - m) - logf(sum);
        uint32_t kk0, kk1, o0, o1;
        tf2x32(0u, 1u, 0u, (uint32_t)t, &kk0, &kk1);
        tf2x32(kk0, kk1, 0u, (uint32_t)(b*VV + v), &o0, &o1);
        uint32_t bits = o0 ^ o1;
        float u = __uint_as_float((bits >> 9) | 0x3F800000u) - 1.0f;
        float g = -logf(-logf(u + 1e-9f) + 1e-9f);
        bv = lp + g; bi = v;
      }
      #pragma unroll
      for (int off = 32; off; off >>= 1){
        float ov = __shfl_xor(bv, off);
        int   oi = __shfl_xor(bi, off);
        if (ov > bv || (ov == bv && oi < bi)){ bv = ov; bi = oi; }
      }
      __syncthreads();
      if (tid < 128 && (tid & 63) == 0){ red[tid >> 6] = bv; redi[tid >> 6] = bi; }
      __syncthreads();
      if (tid == 0){
        float v0 = red[0], v1 = red[1]; int i0 = redi[0], i1 = redi[1];
        P.pred[b*TT + t] = (v1 > v0 || (v1 == v0 && i1 < i0)) ? i1 : i0;
      }
    }
    gbar(P.bar);
  }
}

// ---------------- host ----------------
extern "C" void kernel_launch(void* const* d_in, const int* in_sizes, int n_in,
                              void* d_out, int out_size, void* d_ws, size_t ws_size,
                              hipStream_t stream){
  (void)in_sizes; (void)n_in; (void)out_size; (void)ws_size;
  const float* mol      = (const float*)d_in[1];
  const float* sa_in_w  = (const float*)d_in[3];
  const float* sa_out_w = (const float*)d_in[5];
  const float* ca_in_w  = (const float*)d_in[7];
  const float* ca_in_b  = (const float*)d_in[8];
  const float* ca_out_w = (const float*)d_in[9];
  const float* ca_out_b = (const float*)d_in[10];
  const float* ff_w1    = (const float*)d_in[11];
  const float* ff_w2    = (const float*)d_in[13];
  const float* out_w1   = (const float*)d_in[23];
  const float* out_w2   = (const float*)d_in[25];

  KParams P;
  P.emb = (const float*)d_in[2];
  P.sab = (const float*)d_in[4];
  P.sob = (const float*)d_in[6];
  P.f1b = (const float*)d_in[12];
  P.f2b = (const float*)d_in[14];
  P.g1  = (const float*)d_in[15];
  P.b1  = (const float*)d_in[16];
  P.g2  = (const float*)d_in[17];
  P.b2  = (const float*)d_in[18];
  P.g3  = (const float*)d_in[19];
  P.b3  = (const float*)d_in[20];
  P.fg  = (const float*)d_in[21];
  P.fb  = (const float*)d_in[22];
  P.o1b = (const float*)d_in[24];
  P.o2b = (const float*)d_in[26];
  P.o3w = (const float*)d_in[27];
  P.o3b = (const float*)d_in[28];

  unsigned* bar = (unsigned*)d_ws;          // 1024 uints
  float* ws = (float*)d_ws + 1024;
  float* cosb   = ws;                       // 16384
  float* sinb   = cosb + 16384;             // 16384
  float* ca_tmp = sinb + 16384;             // 65536
  float* cac    = ca_tmp + 65536;           // 65536
  float* kc     = cac + 65536;              // 4194304
  float* vc     = kc + 4194304;             // 4194304
  float* x      = vc + 4194304;             // 16384
  float* qb     = x + 16384;                // 16384
  float* at     = qb + 16384;               // 16384
  float* ao     = at + 16384;               // 16384
  float* h1     = ao + 16384;               // 65536
  float* fo     = h1 + 65536;               // 16384
  float* xf     = fo + 16384;               // 16384
  float* hh1    = xf + 16384;               // 32768
  float* hh2    = hh1 + 32768;              // 32768
  float* sawT   = hh2 + 32768;              // 4*512*1536 = 3145728
  float* sowT   = sawT + 3145728;           // 4*512*512  = 1048576
  float* f1wT   = sowT + 1048576;           // 4*512*2048 = 4194304
  float* f2wT   = f1wT + 4194304;           // 4*2048*512 = 4194304
  float* o1wT   = f2wT + 4194304;           // 512*1024   = 524288
  float* o2wT   = o1wT + 524288;            // 1024*1024  = 1048576

  P.cosb = cosb; P.sinb = sinb; P.cac = cac;
  P.kc = kc; P.vc = vc; P.x = x; P.qb = qb; P.at = at; P.ao = ao;
  P.h1 = h1; P.fo = fo; P.xf = xf; P.hh1 = hh1; P.hh2 = hh2;
  P.sawT = sawT; P.sowT = sowT; P.f1wT = f1wT; P.f2wT = f2wT;
  P.o1wT = o1wT; P.o2wT = o2wT;
  P.pred = (int*)d_out;
  P.bar = bar;

  k_binit<<<1, 1024, 0, stream>>>(bar, P.pred);
  k_tables<<<64, 256, 0, stream>>>(cosb, sinb);
  k_ca1<<<256, 256, 0, stream>>>(mol, ca_in_w, ca_in_b, ca_tmp);
  k_ca2<<<256, 256, 0, stream>>>(ca_tmp, ca_out_w, ca_out_b, cac);

  // weight transposes: [N][K] -> [K][N] per layer
  k_transpose<<<dim3(16,48,4), 256, 0, stream>>>(sa_in_w,  sawT, 1536, 512);
  k_transpose<<<dim3(16,16,4), 256, 0, stream>>>(sa_out_w, sowT,  512, 512);
  k_transpose<<<dim3(16,64,4), 256, 0, stream>>>(ff_w1,    f1wT, 2048, 512);
  k_transpose<<<dim3(64,16,4), 256, 0, stream>>>(ff_w2,    f2wT,  512, 2048);
  k_transpose<<<dim3(16,32,1), 256, 0, stream>>>(out_w1,   o1wT, 1024, 512);
  k_transpose<<<dim3(32,32,1), 256, 0, stream>>>(out_w2,   o2wT, 1024, 1024);

  k_persist<<<NBLK, NTHR, 0, stream>>>(P);
}

// Round 4
// 29980.820 us; speedup vs baseline: 3.1262x; 2.2128x over previous
//
#include <hip/hip_runtime.h>
#include <stdint.h>
#include <stddef.h>

#define BB 32
#define TT 64
#define DD 512
#define HH 8
#define HDIM 64
#define LL 4
#define FFD 2048
#define VV 128

#define NBLK 256
#define NTHR 512

// ---------------- threefry2x32 (20 rounds), matches JAX ----------------
__host__ __device__ inline uint32_t rotl32(uint32_t v, int n){ return (v << n) | (v >> (32 - n)); }

__host__ __device__ inline void tf2x32(uint32_t k0, uint32_t k1, uint32_t x0, uint32_t x1,
                                       uint32_t* o0, uint32_t* o1){
  uint32_t ks2 = k0 ^ k1 ^ 0x1BD11BDAu;
  x0 += k0; x1 += k1;
  x0 += x1; x1 = rotl32(x1,13); x1 ^= x0;
  x0 += x1; x1 = rotl32(x1,15); x1 ^= x0;
  x0 += x1; x1 = rotl32(x1,26); x1 ^= x0;
  x0 += x1; x1 = rotl32(x1, 6); x1 ^= x0;
  x0 += k1; x1 += ks2 + 1u;
  x0 += x1; x1 = rotl32(x1,17); x1 ^= x0;
  x0 += x1; x1 = rotl32(x1,29); x1 ^= x0;
  x0 += x1; x1 = rotl32(x1,16); x1 ^= x0;
  x0 += x1; x1 = rotl32(x1,24); x1 ^= x0;
  x0 += ks2; x1 += k0 + 2u;
  x0 += x1; x1 = rotl32(x1,13); x1 ^= x0;
  x0 += x1; x1 = rotl32(x1,15); x1 ^= x0;
  x0 += x1; x1 = rotl32(x1,26); x1 ^= x0;
  x0 += x1; x1 = rotl32(x1, 6); x1 ^= x0;
  x0 += k0; x1 += k1 + 3u;
  x0 += x1; x1 = rotl32(x1,17); x1 ^= x0;
  x0 += x1; x1 = rotl32(x1,29); x1 ^= x0;
  x0 += x1; x1 = rotl32(x1,16); x1 ^= x0;
  x0 += x1; x1 = rotl32(x1,24); x1 ^= x0;
  x0 += k1; x1 += ks2 + 4u;
  x0 += x1; x1 = rotl32(x1,13); x1 ^= x0;
  x0 += x1; x1 = rotl32(x1,15); x1 ^= x0;
  x0 += x1; x1 = rotl32(x1,26); x1 ^= x0;
  x0 += x1; x1 = rotl32(x1, 6); x1 ^= x0;
  x0 += ks2; x1 += k0 + 5u;
  *o0 = x0; *o1 = x1;
}

// ---------------- helpers ----------------
__device__ inline float dot_f4(const float* __restrict__ a, const float* __restrict__ w, int K){
  float acc = 0.f;
  const float4* a4 = (const float4*)a;
  const float4* w4 = (const float4*)w;
  int K4 = K >> 2;
  for (int k = 0; k < K4; ++k){
    float4 av = a4[k], wv = w4[k];
    acc = fmaf(av.x, wv.x, acc);
    acc = fmaf(av.y, wv.y, acc);
    acc = fmaf(av.z, wv.z, acc);
    acc = fmaf(av.w, wv.w, acc);
  }
  return acc;
}

// LayerNorm across a 512-thread block (one value per thread).
__device__ inline float block_ln(float v, float g, float bb, float* red){
  __syncthreads();
  float s = v;
  #pragma unroll
  for (int off = 32; off; off >>= 1) s += __shfl_xor(s, off);
  if ((threadIdx.x & 63) == 0) red[threadIdx.x >> 6] = s;
  __syncthreads();
  float mu = (red[0]+red[1]+red[2]+red[3]+red[4]+red[5]+red[6]+red[7]) * (1.0f/512.0f);
  float dv = v - mu;
  float sq = dv * dv;
  #pragma unroll
  for (int off = 32; off; off >>= 1) sq += __shfl_xor(sq, off);
  __syncthreads();
  if ((threadIdx.x & 63) == 0) red[threadIdx.x >> 6] = sq;
  __syncthreads();
  float var = (red[0]+red[1]+red[2]+red[3]+red[4]+red[5]+red[6]+red[7]) * (1.0f/512.0f);
  return dv * (1.0f / sqrtf(var + 1e-5f)) * g + bb;
}

// row reduction among the 128 threads (2 waves) owning row j; all 512 threads call.
__device__ inline float row_reduce(float v, int wid, int j, float* wred){
  #pragma unroll
  for (int off = 32; off; off >>= 1) v += __shfl_xor(v, off);
  if ((threadIdx.x & 63) == 0) wred[wid] = v;
  __syncthreads();
  float r = wred[2*j] + wred[2*j+1];
  __syncthreads();
  return r;
}

// ---------------- group barrier: 32 blocks of group g ----------------
__device__ __forceinline__ void gbar(unsigned* bar, int g){
  __syncthreads();
  if (threadIdx.x == 0){
    unsigned* cnt = bar + g*64;
    unsigned* gen = bar + g*64 + 16;
    __builtin_amdgcn_fence(__ATOMIC_RELEASE, "agent");
    unsigned old = __hip_atomic_load(gen, __ATOMIC_RELAXED, __HIP_MEMORY_SCOPE_AGENT);
    if (__hip_atomic_fetch_add(cnt, 1u, __ATOMIC_RELAXED, __HIP_MEMORY_SCOPE_AGENT) == 31u){
      __hip_atomic_store(cnt, 0u, __ATOMIC_RELAXED, __HIP_MEMORY_SCOPE_AGENT);
      __hip_atomic_fetch_add(gen, 1u, __ATOMIC_RELEASE, __HIP_MEMORY_SCOPE_AGENT);
    } else {
      while (__hip_atomic_load(gen, __ATOMIC_RELAXED, __HIP_MEMORY_SCOPE_AGENT) == old)
        __builtin_amdgcn_s_sleep(1);
    }
    __builtin_amdgcn_fence(__ATOMIC_ACQUIRE, "agent");
  }
  __syncthreads();
}

// ---------------- setup kernels ----------------
__global__ void k_tables(float* __restrict__ cosb, float* __restrict__ sinb){
  int tid = blockIdx.x * blockDim.x + threadIdx.x;  // TT*256
  int p = tid >> 8, i = tid & 255;
  float sv = (2.0f * (float)i + 204.8f) / 716.8f;
  float scale = powf(sv, (float)p / 16.0f);
  float invf = 1.0f / powf(10000.0f, (float)i / 256.0f);
  float ang = (float)p * invf;
  cosb[tid] = cosf(ang) * scale;
  sinb[tid] = sinf(ang) * scale;
}

__global__ void k_ca1(const float* __restrict__ mol, const float* __restrict__ w,
                      const float* __restrict__ bias, float* __restrict__ tmp){
  int tid = blockIdx.x * blockDim.x + threadIdx.x;  // LL*BB*DD
  int l = tid >> 14; int r = tid & 16383; int b = r >> 9; int d = r & 511;
  const float* wr = w + (size_t)l*3*DD*DD + (size_t)(2*DD + d)*DD;
  tmp[tid] = bias[l*3*DD + 2*DD + d] + dot_f4(mol + (size_t)b*DD, wr, DD);
}

__global__ void k_ca2(const float* __restrict__ tmp, const float* __restrict__ w,
                      const float* __restrict__ bias, float* __restrict__ cac){
  int tid = blockIdx.x * blockDim.x + threadIdx.x;  // LL*BB*DD
  int l = tid >> 14; int r = tid & 16383; int b = r >> 9; int d = r & 511;
  const float* wr = w + (size_t)l*DD*DD + (size_t)d*DD;
  cac[tid] = bias[l*DD + d] + dot_f4(tmp + ((size_t)l*BB + b)*DD, wr, DD);
}

__global__ void k_binit(unsigned* __restrict__ bar, int* __restrict__ pred){
  int tid = threadIdx.x;            // 1024 threads
  bar[tid] = 0u;
  pred[tid]        = ((tid & (TT-1)) == 0) ? 1 : 0;
  pred[tid + 1024] = (((tid + 1024) & (TT-1)) == 0) ? 1 : 0;
}

// tiled transpose: in [N][K] row-major (+z*N*K) -> out [K][N] (+z*K*N)
__global__ void k_transpose(const float* __restrict__ in, float* __restrict__ out, int N, int K){
  __shared__ float tile[32][33];
  size_t zo = (size_t)blockIdx.z * N * K;
  const float* inp = in + zo;
  float* outp = out + zo;
  int kt = blockIdx.x * 32, nt = blockIdx.y * 32;
  int tx = threadIdx.x & 31, ty = threadIdx.x >> 5;
  for (int r = ty; r < 32; r += 8) tile[r][tx] = inp[(size_t)(nt + r)*K + kt + tx];
  __syncthreads();
  for (int r = ty; r < 32; r += 8) outp[(size_t)(kt + r)*N + nt + tx] = tile[tx][r];
}

// ---------------- persistent decode kernel ----------------
struct KParams {
  const float *emb, *sab, *sob, *f1b, *f2b;
  const float *g1,*b1,*g2,*b2,*g3,*b3,*fg,*fb;
  const float *o1b,*o2b,*o3w,*o3b;
  const float *cosb,*sinb,*cac;
  const float *sawT,*sowT,*f1wT,*f2wT,*o1wT,*o2wT;
  float *kc,*vc,*xl,*qb,*at,*ao,*x2,*fo,*h1,*xf,*hh1,*hh2,*ps3;
  int *pred;
  unsigned *bar;
};

__global__ __launch_bounds__(NTHR) void k_persist(KParams P){
  const int bid = blockIdx.x, tid = threadIdx.x;
  const int g = bid & 7;          // group (XCD-aligned under %8 round-robin; perf hint only)
  const int m = bid >> 3;         // member 0..31
  const int wid = tid >> 6, lane = tid & 63;
  __shared__ __align__(16) float smem[8704];

  for (int t = 1; t < TT; ++t){
    const int pp = t - 1;

    for (int l = 0; l < LL; ++l){
      // ================= S1: build x_l + QKV (24 blocks n-sliced) =================
      {
        float* sx   = smem;          // [4][512]
        float* part = smem + 2048;   // [8][4][64]
        float* srow = smem + 4096;   // [4][2]
        const int j = tid >> 7, d4 = (tid & 127) * 4;
        const int rb = g*4 + j;
        if (l == 0){
          int tok = P.pred[rb*TT + pp];
          #pragma unroll
          for (int e = d4; e < d4 + 4; e += 2){
            int i = e >> 1;
            float c = P.cosb[pp*256 + i], s = P.sinb[pp*256 + i];
            float e0 = P.emb[(size_t)tok*DD + e];
            float e1 = P.emb[(size_t)tok*DD + e + 1];
            sx[j*512 + e]     = fmaf(e0, c, -(e1*s));
            sx[j*512 + e + 1] = fmaf(e1, c, e0*s);
          }
        } else {
          if (tid < 4){
            float a = 0.f, bq = 0.f;
            const float* pr = P.ps3 + (size_t)(g*4 + tid)*64;
            for (int s = 0; s < 32; ++s){ a += pr[s*2]; bq += pr[s*2+1]; }
            float mu = a * (1.0f/512.0f);
            float var = bq * (1.0f/512.0f) - mu*mu;
            srow[tid*2]   = mu;
            srow[tid*2+1] = 1.0f / sqrtf(var + 1e-5f);
          }
          __syncthreads();
          float mu = srow[j*2], rs = srow[j*2+1];
          float4 xv = *(const float4*)&P.x2[(size_t)rb*DD + d4];
          float4 fv = *(const float4*)&P.fo[(size_t)rb*DD + d4];
          const float* g3r = P.g3 + (size_t)(l-1)*DD;
          const float* b3r = P.b3 + (size_t)(l-1)*DD;
          float yv[4] = {xv.x+fv.x, xv.y+fv.y, xv.z+fv.z, xv.w+fv.w};
          #pragma unroll
          for (int i = 0; i < 4; ++i)
            sx[j*512 + d4 + i] = (yv[i]-mu)*rs*g3r[d4+i] + b3r[d4+i];
        }
        __syncthreads();
        if (m == 0){   // materialize x_l
          float4 v = *(float4*)&sx[j*512 + d4];
          *(float4*)&P.xl[(size_t)rb*DD + d4] = v;
        }
        if (m < 24){
          const int n0 = m*64;
          const float* wp = P.sawT + (size_t)l*512*1536 + (size_t)(wid*64)*1536 + n0 + lane;
          const int kb = wid*64;
          float a0=0.f,a1=0.f,a2=0.f,a3=0.f;
          for (int k4 = 0; k4 < 16; ++k4){
            float w0 = wp[(k4*4+0)*1536];
            float w1 = wp[(k4*4+1)*1536];
            float w2 = wp[(k4*4+2)*1536];
            float w3 = wp[(k4*4+3)*1536];
            float4 xa = *(const float4*)&sx[0*512 + kb + k4*4];
            float4 xb = *(const float4*)&sx[1*512 + kb + k4*4];
            float4 xc = *(const float4*)&sx[2*512 + kb + k4*4];
            float4 xd = *(const float4*)&sx[3*512 + kb + k4*4];
            a0=fmaf(w0,xa.x,a0); a0=fmaf(w1,xa.y,a0); a0=fmaf(w2,xa.z,a0); a0=fmaf(w3,xa.w,a0);
            a1=fmaf(w0,xb.x,a1); a1=fmaf(w1,xb.y,a1); a1=fmaf(w2,xb.z,a1); a1=fmaf(w3,xb.w,a1);
            a2=fmaf(w0,xc.x,a2); a2=fmaf(w1,xc.y,a2); a2=fmaf(w2,xc.z,a2); a2=fmaf(w3,xc.w,a2);
            a3=fmaf(w0,xd.x,a3); a3=fmaf(w1,xd.y,a3); a3=fmaf(w2,xd.z,a3); a3=fmaf(w3,xd.w,a3);
          }
          part[(wid*4+0)*64 + lane] = a0;
          part[(wid*4+1)*64 + lane] = a1;
          part[(wid*4+2)*64 + lane] = a2;
          part[(wid*4+3)*64 + lane] = a3;
          __syncthreads();
          if (tid < 256){
            int jr = tid >> 6, nl = tid & 63;
            int n = n0 + nl, rb2 = g*4 + jr;
            float s = P.sab[l*1536 + n];
            #pragma unroll
            for (int w = 0; w < 8; ++w) s += part[(w*4+jr)*64 + nl];
            if (n < DD){
              P.qb[(size_t)rb2*DD + n] = s;
            } else if (n < 2*DD){
              int h = (n - DD) >> 6, hd = (n - DD) & 63;
              P.kc[((((size_t)l*BB + rb2)*HH + h)*TT + pp)*HDIM + hd] = s;
            } else {
              int h = (n - 2*DD) >> 6, hd = (n - 2*DD) & 63;
              P.vc[((((size_t)l*BB + rb2)*HH + h)*TT + pp)*HDIM + hd] = s;
            }
          }
        }
      }
      gbar(P.bar, g);

      // ================= S2: attention (32 blocks = (row,head), 1 wave) =================
      {
        int bl = m >> 3, h = m & 7, rb = g*4 + bl;
        float* qs = smem; float* ps = smem + 64;
        if (tid < 64) qs[tid] = P.qb[(size_t)rb*DD + h*HDIM + tid];
        __syncthreads();
        if (tid < 64){
          const float* kb = P.kc + (((size_t)l*BB + rb)*HH + h)*TT*HDIM;
          float s = -INFINITY;
          if (lane <= pp && P.pred[rb*TT + lane] != 0){
            const float* kr = kb + lane*HDIM;
            float acc = 0.f;
            #pragma unroll
            for (int k2 = 0; k2 < HDIM; ++k2) acc = fmaf(qs[k2], kr[k2], acc);
            s = acc * 0.125f;
          }
          float mx = s;
          #pragma unroll
          for (int off = 32; off; off >>= 1) mx = fmaxf(mx, __shfl_xor(mx, off));
          float e = (s == -INFINITY) ? 0.f : expf(s - mx);
          float sum = e;
          #pragma unroll
          for (int off = 32; off; off >>= 1) sum += __shfl_xor(sum, off);
          ps[lane] = e / sum;
          const float* vb = P.vc + (((size_t)l*BB + rb)*HH + h)*TT*HDIM;
          float o = 0.f;
          int jj = 0;
          for (; jj + 8 <= t; jj += 8){
            float vv[8];
            #pragma unroll
            for (int u = 0; u < 8; ++u) vv[u] = vb[(jj+u)*HDIM + lane];
            #pragma unroll
            for (int u = 0; u < 8; ++u) o = fmaf(ps[jj+u], vv[u], o);
          }
          for (; jj <= pp; ++jj) o = fmaf(ps[jj], vb[jj*HDIM + lane], o);
          P.at[(size_t)rb*DD + h*HDIM + lane] = o;
        }
      }
      gbar(P.bar, g);

      // ================= S3: oproj (32 blocks, 16 cols each) =================
      {
        float* ats  = smem;          // [4][512]
        float* part = smem + 2048;   // [8][64]
        const int j = tid >> 7, d4 = (tid & 127) * 4;
        *(float4*)&ats[j*512 + d4] = *(const float4*)&P.at[(size_t)(g*4+j)*DD + d4];
        __syncthreads();
        const int n0 = m*16;
        const int jb = lane >> 4, nc = lane & 15;
        const float* wp = P.sowT + (size_t)l*512*512 + (size_t)(wid*64)*512 + n0 + nc;
        const int kb = wid*64;
        float acc = 0.f;
        for (int k4 = 0; k4 < 16; ++k4){
          float w0 = wp[(k4*4+0)*512];
          float w1 = wp[(k4*4+1)*512];
          float w2 = wp[(k4*4+2)*512];
          float w3 = wp[(k4*4+3)*512];
          float4 xa = *(const float4*)&ats[jb*512 + kb + k4*4];
          acc=fmaf(w0,xa.x,acc); acc=fmaf(w1,xa.y,acc); acc=fmaf(w2,xa.z,acc); acc=fmaf(w3,xa.w,acc);
        }
        part[wid*64 + lane] = acc;
        __syncthreads();
        if (tid < 64){
          int jb2 = tid >> 4, nc2 = tid & 15, n = n0 + nc2;
          float s = P.sob[l*DD + n];
          #pragma unroll
          for (int w = 0; w < 8; ++w) s += part[w*64 + jb2*16 + nc2];
          P.ao[(size_t)(g*4+jb2)*DD + n] = s;
        }
      }
      gbar(P.bar, g);

      // ================= S4: ln1+ln2 (redundant) + FF1 (32 blocks, 64 cols) =================
      {
        float* sx2  = smem;          // [4][512]
        float* part = smem + 2048;   // [8][4][64]
        float* wred = smem + 4096;   // [8]
        const int j = tid >> 7, d4 = (tid & 127) * 4;
        const int rb = g*4 + j;
        float4 xlv = *(const float4*)&P.xl[(size_t)rb*DD + d4];
        float4 aov = *(const float4*)&P.ao[(size_t)rb*DD + d4];
        float y[4] = {xlv.x+aov.x, xlv.y+aov.y, xlv.z+aov.z, xlv.w+aov.w};
        float s = ((y[0]+y[1])+y[2])+y[3];
        float mu = row_reduce(s, wid, j, wred) * (1.0f/512.0f);
        float dv[4], sq = 0.f;
        #pragma unroll
        for (int i = 0; i < 4; ++i){ dv[i] = y[i]-mu; sq += dv[i]*dv[i]; }
        float rs = 1.0f / sqrtf(row_reduce(sq, wid, j, wred) * (1.0f/512.0f) + 1e-5f);
        float z[4];
        #pragma unroll
        for (int i = 0; i < 4; ++i){
          int d = d4 + i;
          z[i] = dv[i]*rs*P.g1[l*DD+d] + P.b1[l*DD+d] + P.cac[((size_t)l*BB + rb)*DD + d];
        }
        float s2 = ((z[0]+z[1])+z[2])+z[3];
        float mu2 = row_reduce(s2, wid, j, wred) * (1.0f/512.0f);
        float dz[4], sq2 = 0.f;
        #pragma unroll
        for (int i = 0; i < 4; ++i){ dz[i] = z[i]-mu2; sq2 += dz[i]*dz[i]; }
        float rs2 = 1.0f / sqrtf(row_reduce(sq2, wid, j, wred) * (1.0f/512.0f) + 1e-5f);
        float x2v[4];
        #pragma unroll
        for (int i = 0; i < 4; ++i){
          int d = d4 + i;
          x2v[i] = dz[i]*rs2*P.g2[l*DD+d] + P.b2[l*DD+d];
          sx2[j*512 + d] = x2v[i];
        }
        if (m == 0) *(float4*)&P.x2[(size_t)rb*DD + d4] = make_float4(x2v[0],x2v[1],x2v[2],x2v[3]);
        __syncthreads();
        // ff1 dot
        const int n0 = m*64;
        const float* wp = P.f1wT + (size_t)l*512*2048 + (size_t)(wid*64)*2048 + n0 + lane;
        const int kb = wid*64;
        float a0=0.f,a1=0.f,a2=0.f,a3=0.f;
        for (int k4 = 0; k4 < 16; ++k4){
          float w0 = wp[(k4*4+0)*2048];
          float w1 = wp[(k4*4+1)*2048];
          float w2 = wp[(k4*4+2)*2048];
          float w3 = wp[(k4*4+3)*2048];
          float4 xa = *(const float4*)&sx2[0*512 + kb + k4*4];
          float4 xb = *(const float4*)&sx2[1*512 + kb + k4*4];
          float4 xc = *(const float4*)&sx2[2*512 + kb + k4*4];
          float4 xd = *(const float4*)&sx2[3*512 + kb + k4*4];
          a0=fmaf(w0,xa.x,a0); a0=fmaf(w1,xa.y,a0); a0=fmaf(w2,xa.z,a0); a0=fmaf(w3,xa.w,a0);
          a1=fmaf(w0,xb.x,a1); a1=fmaf(w1,xb.y,a1); a1=fmaf(w2,xb.z,a1); a1=fmaf(w3,xb.w,a1);
          a2=fmaf(w0,xc.x,a2); a2=fmaf(w1,xc.y,a2); a2=fmaf(w2,xc.z,a2); a2=fmaf(w3,xc.w,a2);
          a3=fmaf(w0,xd.x,a3); a3=fmaf(w1,xd.y,a3); a3=fmaf(w2,xd.z,a3); a3=fmaf(w3,xd.w,a3);
        }
        part[(wid*4+0)*64 + lane] = a0;
        part[(wid*4+1)*64 + lane] = a1;
        part[(wid*4+2)*64 + lane] = a2;
        part[(wid*4+3)*64 + lane] = a3;
        __syncthreads();
        if (tid < 256){
          int jr = tid >> 6, nl = tid & 63;
          int n = n0 + nl;
          float v = P.f1b[l*FFD + n];
          #pragma unroll
          for (int w = 0; w < 8; ++w) v += part[(w*4+jr)*64 + nl];
          P.h1[(size_t)(g*4+jr)*FFD + n] = v / (1.0f + expf(-v));
        }
      }
      gbar(P.bar, g);

      // ================= S5: FF2 (32 blocks, 16 cols) + ln3 partials =================
      {
        float* sh1  = smem;          // [4][2048]
        float* part = smem + 8192;   // [8][64]
        #pragma unroll
        for (int q = 0; q < 4; ++q){
          int fi = tid + q*512;               // float4 index over [4][512]
          int j = fi >> 9, c4 = fi & 511;
          *(float4*)&sh1[j*2048 + c4*4] = *(const float4*)&P.h1[(size_t)(g*4+j)*FFD + c4*4];
        }
        __syncthreads();
        const int n0 = m*16;
        const int jb = lane >> 4, nc = lane & 15;
        const float* wp = P.f2wT + (size_t)l*2048*512 + (size_t)(wid*256)*512 + n0 + nc;
        const int kb = wid*256;
        float acc = 0.f;
        for (int k4 = 0; k4 < 64; ++k4){
          float w0 = wp[(k4*4+0)*512];
          float w1 = wp[(k4*4+1)*512];
          float w2 = wp[(k4*4+2)*512];
          float w3 = wp[(k4*4+3)*512];
          float4 xa = *(const float4*)&sh1[jb*2048 + kb + k4*4];
          acc=fmaf(w0,xa.x,acc); acc=fmaf(w1,xa.y,acc); acc=fmaf(w2,xa.z,acc); acc=fmaf(w3,xa.w,acc);
        }
        part[wid*64 + lane] = acc;
        __syncthreads();
        if (tid < 64){
          int jb2 = tid >> 4, nc2 = tid & 15, n = n0 + nc2;
          int rb2 = g*4 + jb2;
          float val = P.f2b[l*DD + n];
          #pragma unroll
          for (int w = 0; w < 8; ++w) val += part[w*64 + jb2*16 + nc2];
          P.fo[(size_t)rb2*DD + n] = val;
          float y = P.x2[(size_t)rb2*DD + n] + val;
          float s1 = y, sq = y*y;
          #pragma unroll
          for (int off = 1; off < 16; off <<= 1){
            s1 += __shfl_xor(s1, off);
            sq += __shfl_xor(sq, off);
          }
          if (nc2 == 0){
            P.ps3[(size_t)(rb2*32 + m)*2]     = s1;
            P.ps3[(size_t)(rb2*32 + m)*2 + 1] = sq;
          }
        }
      }
      gbar(P.bar, g);
    }

    // ================= S6: final ln3 + fn ln (4 row blocks) =================
    if (m < 4){
      int rb = g*4 + m, d = tid;
      float y = P.x2[(size_t)rb*DD + d] + P.fo[(size_t)rb*DD + d];
      float xv = block_ln(y, P.g3[3*DD + d], P.b3[3*DD + d], smem);
      float o  = block_ln(xv, P.fg[d], P.fb[d], smem);
      P.xf[(size_t)rb*DD + d] = o;
    }
    gbar(P.bar, g);

    // ================= S7: head1 (32 blocks, 32 cols) =================
    {
      float* sxf  = smem;          // [4][512]
      float* part = smem + 2048;   // [8][2][64]
      const int j = tid >> 7, d4 = (tid & 127) * 4;
      *(float4*)&sxf[j*512 + d4] = *(const float4*)&P.xf[(size_t)(g*4+j)*DD + d4];
      __syncthreads();
      const int n0 = m*32;
      const int jh = lane >> 5, nc = lane & 31;
      const float* wp = P.o1wT + (size_t)(wid*64)*1024 + n0 + nc;
      const int kb = wid*64;
      float ac0 = 0.f, ac1 = 0.f;
      for (int k4 = 0; k4 < 16; ++k4){
        float w0 = wp[(k4*4+0)*1024];
        float w1 = wp[(k4*4+1)*1024];
        float w2 = wp[(k4*4+2)*1024];
        float w3 = wp[(k4*4+3)*1024];
        float4 xa = *(const float4*)&sxf[jh*512 + kb + k4*4];
        float4 xb = *(const float4*)&sxf[(jh+2)*512 + kb + k4*4];
        ac0=fmaf(w0,xa.x,ac0); ac0=fmaf(w1,xa.y,ac0); ac0=fmaf(w2,xa.z,ac0); ac0=fmaf(w3,xa.w,ac0);
        ac1=fmaf(w0,xb.x,ac1); ac1=fmaf(w1,xb.y,ac1); ac1=fmaf(w2,xb.z,ac1); ac1=fmaf(w3,xb.w,ac1);
      }
      part[(wid*2+0)*64 + lane] = ac0;
      part[(wid*2+1)*64 + lane] = ac1;
      __syncthreads();
      if (tid < 128){
        int row = tid >> 5, nc2 = tid & 31;
        int r = row >> 1, jh2 = row & 1;
        float s = P.o1b[n0 + nc2];
        #pragma unroll
        for (int w = 0; w < 8; ++w) s += part[(w*2+r)*64 + jh2*32 + nc2];
        float a = s;
        P.hh1[(size_t)(g*4+row)*1024 + n0 + nc2] = 0.5f * a * (1.0f + erff(a / 1.41421356237309504880f));
      }
    }
    gbar(P.bar, g);

    // ================= S8: head2 (32 blocks, 32 cols, K=1024) =================
    {
      float* sh   = smem;          // [4][1024]
      float* part = smem + 4096;   // [8][2][64]
      #pragma unroll
      for (int q = 0; q < 2; ++q){
        int fi = tid + q*512;               // float4 index over [4][256]
        int j = fi >> 8, c4 = fi & 255;
        *(float4*)&sh[j*1024 + c4*4] = *(const float4*)&P.hh1[(size_t)(g*4+j)*1024 + c4*4];
      }
      __syncthreads();
      const int n0 = m*32;
      const int jh = lane >> 5, nc = lane & 31;
      const float* wp = P.o2wT + (size_t)(wid*128)*1024 + n0 + nc;
      const int kb = wid*128;
      float ac0 = 0.f, ac1 = 0.f;
      for (int k4 = 0; k4 < 32; ++k4){
        float w0 = wp[(k4*4+0)*1024];
        float w1 = wp[(k4*4+1)*1024];
        float w2 = wp[(k4*4+2)*1024];
        float w3 = wp[(k4*4+3)*1024];
        float4 xa = *(const float4*)&sh[jh*1024 + kb + k4*4];
        float4 xb = *(const float4*)&sh[(jh+2)*1024 + kb + k4*4];
        ac0=fmaf(w0,xa.x,ac0); ac0=fmaf(w1,xa.y,ac0); ac0=fmaf(w2,xa.z,ac0); ac0=fmaf(w3,xa.w,ac0);
        ac1=fmaf(w0,xb.x,ac1); ac1=fmaf(w1,xb.y,ac1); ac1=fmaf(w2,xb.z,ac1); ac1=fmaf(w3,xb.w,ac1);
      }
      part[(wid*2+0)*64 + lane] = ac0;
      part[(wid*2+1)*64 + lane] = ac1;
      __syncthreads();
      if (tid < 128){
        int row = tid >> 5, nc2 = tid & 31;
        int r = row >> 1, jh2 = row & 1;
        float s = P.o2b[n0 + nc2];
        #pragma unroll
        for (int w = 0; w < 8; ++w) s += part[(w*2+r)*64 + jh2*32 + nc2];
        float a = s;
        P.hh2[(size_t)(g*4+row)*1024 + n0 + nc2] = 0.5f * a * (1.0f + erff(a / 1.41421356237309504880f));
      }
    }
    gbar(P.bar, g);

    // ================= S9: sample (4 row blocks; exact round-3 math) =================
    if (m < 4){
      int rb = g*4 + m, v = tid;
      float* hrow = smem;                 // 1024
      float* red  = smem + 1024;          // 8
      int*   redi = (int*)(smem + 1032);  // 2
      for (int k = tid; k < 1024; k += NTHR) hrow[k] = P.hh2[(size_t)rb*1024 + k];
      __syncthreads();
      float sv = 0.f;
      if (tid < 128){
        float acc = P.o3b[v] + dot_f4(hrow, P.o3w + (size_t)v*1024, 1024);
        sv = acc / 0.1f;
      }
      float mx = (tid < 128) ? sv : -INFINITY;
      #pragma unroll
      for (int off = 32; off; off >>= 1) mx = fmaxf(mx, __shfl_xor(mx, off));
      __syncthreads();
      if (tid < 128 && (tid & 63) == 0) red[tid >> 6] = mx;
      __syncthreads();
      mx = fmaxf(red[0], red[1]);
      float e = (tid < 128) ? expf(sv - mx) : 0.f;
      float sum = e;
      #pragma unroll
      for (int off = 32; off; off >>= 1) sum += __shfl_xor(sum, off);
      __syncthreads();
      if (tid < 128 && (tid & 63) == 0) red[tid >> 6] = sum;
      __syncthreads();
      sum = red[0] + red[1];
      float bv = -INFINITY; int bi = 0x7fffffff;
      if (tid < 128){
        float lp = (sv - mx) - logf(sum);
        uint32_t kk0, kk1, o0, o1;
        tf2x32(0u, 1u, 0u, (uint32_t)t, &kk0, &kk1);
        tf2x32(kk0, kk1, 0u, (uint32_t)(rb*VV + v), &o0, &o1);
        uint32_t bits = o0 ^ o1;
        float u = __uint_as_float((bits >> 9) | 0x3F800000u) - 1.0f;
        float gg = -logf(-logf(u + 1e-9f) + 1e-9f);
        bv = lp + gg; bi = v;
      }
      #pragma unroll
      for (int off = 32; off; off >>= 1){
        float ov = __shfl_xor(bv, off);
        int   oi = __shfl_xor(bi, off);
        if (ov > bv || (ov == bv && oi < bi)){ bv = ov; bi = oi; }
      }
      __syncthreads();
      if (tid < 128 && (tid & 63) == 0){ red[tid >> 6] = bv; redi[tid >> 6] = bi; }
      __syncthreads();
      if (tid == 0){
        float v0 = red[0], v1 = red[1]; int i0 = redi[0], i1 = redi[1];
        P.pred[rb*TT + t] = (v1 > v0 || (v1 == v0 && i1 < i0)) ? i1 : i0;
      }
    }
    gbar(P.bar, g);
  }
}

// ---------------- host ----------------
extern "C" void kernel_launch(void* const* d_in, const int* in_sizes, int n_in,
                              void* d_out, int out_size, void* d_ws, size_t ws_size,
                              hipStream_t stream){
  (void)in_sizes; (void)n_in; (void)out_size; (void)ws_size;
  const float* mol      = (const float*)d_in[1];
  const float* sa_in_w  = (const float*)d_in[3];
  const float* sa_out_w = (const float*)d_in[5];
  const float* ca_in_w  = (const float*)d_in[7];
  const float* ca_in_b  = (const float*)d_in[8];
  const float* ca_out_w = (const float*)d_in[9];
  const float* ca_out_b = (const float*)d_in[10];
  const float* ff_w1    = (const float*)d_in[11];
  const float* ff_w2    = (const float*)d_in[13];
  const float* out_w1   = (const float*)d_in[23];
  const float* out_w2   = (const float*)d_in[25];

  KParams P;
  P.emb = (const float*)d_in[2];
  P.sab = (const float*)d_in[4];
  P.sob = (const float*)d_in[6];
  P.f1b = (const float*)d_in[12];
  P.f2b = (const float*)d_in[14];
  P.g1  = (const float*)d_in[15];
  P.b1  = (const float*)d_in[16];
  P.g2  = (const float*)d_in[17];
  P.b2  = (const float*)d_in[18];
  P.g3  = (const float*)d_in[19];
  P.b3  = (const float*)d_in[20];
  P.fg  = (const float*)d_in[21];
  P.fb  = (const float*)d_in[22];
  P.o1b = (const float*)d_in[24];
  P.o2b = (const float*)d_in[26];
  P.o3w = (const float*)d_in[27];
  P.o3b = (const float*)d_in[28];

  unsigned* bar = (unsigned*)d_ws;          // 1024 uints
  float* ws = (float*)d_ws + 1024;
  float* cosb   = ws;                       // 16384
  float* sinb   = cosb + 16384;             // 16384
  float* ca_tmp = sinb + 16384;             // 65536
  float* cac    = ca_tmp + 65536;           // 65536
  float* kc     = cac + 65536;              // 4194304
  float* vc     = kc + 4194304;             // 4194304
  float* xl     = vc + 4194304;             // 16384
  float* qb     = xl + 16384;               // 16384
  float* at     = qb + 16384;               // 16384
  float* ao     = at + 16384;               // 16384
  float* x2     = ao + 16384;               // 16384
  float* fo     = x2 + 16384;               // 16384
  float* h1     = fo + 16384;               // 65536
  float* xf     = h1 + 65536;               // 16384
  float* hh1    = xf + 16384;               // 32768
  float* hh2    = hh1 + 32768;              // 32768
  float* ps3    = hh2 + 32768;              // 2048
  float* sawT   = ps3 + 2048;               // 3145728
  float* sowT   = sawT + 3145728;           // 1048576
  float* f1wT   = sowT + 1048576;           // 4194304
  float* f2wT   = f1wT + 4194304;           // 4194304
  float* o1wT   = f2wT + 4194304;           // 524288
  float* o2wT   = o1wT + 524288;            // 1048576

  P.cosb = cosb; P.sinb = sinb; P.cac = cac;
  P.kc = kc; P.vc = vc; P.xl = xl; P.qb = qb; P.at = at; P.ao = ao;
  P.x2 = x2; P.fo = fo; P.h1 = h1; P.xf = xf; P.hh1 = hh1; P.hh2 = hh2;
  P.ps3 = ps3;
  P.sawT = sawT; P.sowT = sowT; P.f1wT = f1wT; P.f2wT = f2wT;
  P.o1wT = o1wT; P.o2wT = o2wT;
  P.pred = (int*)d_out;
  P.bar = bar;

  k_binit<<<1, 1024, 0, stream>>>(bar, P.pred);
  k_tables<<<64, 256, 0, stream>>>(cosb, sinb);
  k_ca1<<<256, 256, 0, stream>>>(mol, ca_in_w, ca_in_b, ca_tmp);
  k_ca2<<<256, 256, 0, stream>>>(ca_tmp, ca_out_w, ca_out_b, cac);

  k_transpose<<<dim3(16,48,4), 256, 0, stream>>>(sa_in_w,  sawT, 1536, 512);
  k_transpose<<<dim3(16,16,4), 256, 0, stream>>>(sa_out_w, sowT,  512, 512);
  k_transpose<<<dim3(16,64,4), 256, 0, stream>>>(ff_w1,    f1wT, 2048, 512);
  k_transpose<<<dim3(64,16,4), 256, 0, stream>>>(ff_w2,    f2wT,  512, 2048);
  k_transpose<<<dim3(16,32,1), 256, 0, stream>>>(out_w1,   o1wT, 1024, 512);
  k_transpose<<<dim3(32,32,1), 256, 0, stream>>>(out_w2,   o2wT, 1024, 1024);

  k_persist<<<NBLK, NTHR, 0, stream>>>(P);
}

// Round 5
// 25574.348 us; speedup vs baseline: 3.6649x; 1.1723x over previous
//
#include <hip/hip_runtime.h>
#include <stdint.h>
#include <stddef.h>

#define BB 32
#define TT 64
#define DD 512
#define HH 8
#define HDIM 64
#define LL 4
#define FFD 2048
#define VV 128

#define NBLK 256
#define NTHR 512

// ---------------- threefry2x32 (20 rounds), matches JAX ----------------
__host__ __device__ inline uint32_t rotl32(uint32_t v, int n){ return (v << n) | (v >> (32 - n)); }

__host__ __device__ inline void tf2x32(uint32_t k0, uint32_t k1, uint32_t x0, uint32_t x1,
                                       uint32_t* o0, uint32_t* o1){
  uint32_t ks2 = k0 ^ k1 ^ 0x1BD11BDAu;
  x0 += k0; x1 += k1;
  x0 += x1; x1 = rotl32(x1,13); x1 ^= x0;
  x0 += x1; x1 = rotl32(x1,15); x1 ^= x0;
  x0 += x1; x1 = rotl32(x1,26); x1 ^= x0;
  x0 += x1; x1 = rotl32(x1, 6); x1 ^= x0;
  x0 += k1; x1 += ks2 + 1u;
  x0 += x1; x1 = rotl32(x1,17); x1 ^= x0;
  x0 += x1; x1 = rotl32(x1,29); x1 ^= x0;
  x0 += x1; x1 = rotl32(x1,16); x1 ^= x0;
  x0 += x1; x1 = rotl32(x1,24); x1 ^= x0;
  x0 += ks2; x1 += k0 + 2u;
  x0 += x1; x1 = rotl32(x1,13); x1 ^= x0;
  x0 += x1; x1 = rotl32(x1,15); x1 ^= x0;
  x0 += x1; x1 = rotl32(x1,26); x1 ^= x0;
  x0 += x1; x1 = rotl32(x1, 6); x1 ^= x0;
  x0 += k0; x1 += k1 + 3u;
  x0 += x1; x1 = rotl32(x1,17); x1 ^= x0;
  x0 += x1; x1 = rotl32(x1,29); x1 ^= x0;
  x0 += x1; x1 = rotl32(x1,16); x1 ^= x0;
  x0 += x1; x1 = rotl32(x1,24); x1 ^= x0;
  x0 += k1; x1 += ks2 + 4u;
  x0 += x1; x1 = rotl32(x1,13); x1 ^= x0;
  x0 += x1; x1 = rotl32(x1,15); x1 ^= x0;
  x0 += x1; x1 = rotl32(x1,26); x1 ^= x0;
  x0 += x1; x1 = rotl32(x1, 6); x1 ^= x0;
  x0 += ks2; x1 += k0 + 5u;
  *o0 = x0; *o1 = x1;
}

// ---------------- helpers ----------------
__device__ inline float dot_f4(const float* __restrict__ a, const float* __restrict__ w, int K){
  float acc = 0.f;
  const float4* a4 = (const float4*)a;
  const float4* w4 = (const float4*)w;
  int K4 = K >> 2;
  for (int k = 0; k < K4; ++k){
    float4 av = a4[k], wv = w4[k];
    acc = fmaf(av.x, wv.x, acc);
    acc = fmaf(av.y, wv.y, acc);
    acc = fmaf(av.z, wv.z, acc);
    acc = fmaf(av.w, wv.w, acc);
  }
  return acc;
}

// LayerNorm across a 512-thread block (one value per thread).
__device__ inline float block_ln(float v, float g, float bb, float* red){
  __syncthreads();
  float s = v;
  #pragma unroll
  for (int off = 32; off; off >>= 1) s += __shfl_xor(s, off);
  if ((threadIdx.x & 63) == 0) red[threadIdx.x >> 6] = s;
  __syncthreads();
  float mu = (red[0]+red[1]+red[2]+red[3]+red[4]+red[5]+red[6]+red[7]) * (1.0f/512.0f);
  float dv = v - mu;
  float sq = dv * dv;
  #pragma unroll
  for (int off = 32; off; off >>= 1) sq += __shfl_xor(sq, off);
  __syncthreads();
  if ((threadIdx.x & 63) == 0) red[threadIdx.x >> 6] = sq;
  __syncthreads();
  float var = (red[0]+red[1]+red[2]+red[3]+red[4]+red[5]+red[6]+red[7]) * (1.0f/512.0f);
  return dv * (1.0f / sqrtf(var + 1e-5f)) * g + bb;
}

// row reduction among the 128 threads (2 waves) owning row j; all 512 threads call.
__device__ inline float row_reduce(float v, int wid, int j, float* wred){
  #pragma unroll
  for (int off = 32; off; off >>= 1) v += __shfl_xor(v, off);
  if ((threadIdx.x & 63) == 0) wred[wid] = v;
  __syncthreads();
  float r = wred[2*j] + wred[2*j+1];
  __syncthreads();
  return r;
}

// ---------------- group barrier: 32 blocks of group g ----------------
__device__ __forceinline__ void gbar(unsigned* bar, int g){
  __syncthreads();
  if (threadIdx.x == 0){
    unsigned* cnt = bar + g*64;
    unsigned* gen = bar + g*64 + 16;
    __builtin_amdgcn_fence(__ATOMIC_RELEASE, "agent");
    unsigned old = __hip_atomic_load(gen, __ATOMIC_RELAXED, __HIP_MEMORY_SCOPE_AGENT);
    if (__hip_atomic_fetch_add(cnt, 1u, __ATOMIC_RELAXED, __HIP_MEMORY_SCOPE_AGENT) == 31u){
      __hip_atomic_store(cnt, 0u, __ATOMIC_RELAXED, __HIP_MEMORY_SCOPE_AGENT);
      __hip_atomic_fetch_add(gen, 1u, __ATOMIC_RELEASE, __HIP_MEMORY_SCOPE_AGENT);
    } else {
      while (__hip_atomic_load(gen, __ATOMIC_RELAXED, __HIP_MEMORY_SCOPE_AGENT) == old)
        __builtin_amdgcn_s_sleep(1);
    }
    __builtin_amdgcn_fence(__ATOMIC_ACQUIRE, "agent");
  }
  __syncthreads();
}

// ---------------- setup kernels ----------------
__global__ void k_tables(float* __restrict__ cosb, float* __restrict__ sinb){
  int tid = blockIdx.x * blockDim.x + threadIdx.x;  // TT*256
  int p = tid >> 8, i = tid & 255;
  float sv = (2.0f * (float)i + 204.8f) / 716.8f;
  float scale = powf(sv, (float)p / 16.0f);
  float invf = 1.0f / powf(10000.0f, (float)i / 256.0f);
  float ang = (float)p * invf;
  cosb[tid] = cosf(ang) * scale;
  sinb[tid] = sinf(ang) * scale;
}

__global__ void k_ca1(const float* __restrict__ mol, const float* __restrict__ w,
                      const float* __restrict__ bias, float* __restrict__ tmp){
  int tid = blockIdx.x * blockDim.x + threadIdx.x;  // LL*BB*DD
  int l = tid >> 14; int r = tid & 16383; int b = r >> 9; int d = r & 511;
  const float* wr = w + (size_t)l*3*DD*DD + (size_t)(2*DD + d)*DD;
  tmp[tid] = bias[l*3*DD + 2*DD + d] + dot_f4(mol + (size_t)b*DD, wr, DD);
}

__global__ void k_ca2(const float* __restrict__ tmp, const float* __restrict__ w,
                      const float* __restrict__ bias, float* __restrict__ cac){
  int tid = blockIdx.x * blockDim.x + threadIdx.x;  // LL*BB*DD
  int l = tid >> 14; int r = tid & 16383; int b = r >> 9; int d = r & 511;
  const float* wr = w + (size_t)l*DD*DD + (size_t)d*DD;
  cac[tid] = bias[l*DD + d] + dot_f4(tmp + ((size_t)l*BB + b)*DD, wr, DD);
}

__global__ void k_binit(unsigned* __restrict__ bar, int* __restrict__ pred){
  int tid = threadIdx.x;            // 1024 threads
  bar[tid] = 0u;
  pred[tid]        = ((tid & (TT-1)) == 0) ? 1 : 0;
  pred[tid + 1024] = (((tid + 1024) & (TT-1)) == 0) ? 1 : 0;
}

// k4-pack: in [L][N][K] row-major -> out [L][K/4][N][4]
// out[l][k>>2][n][k&3] = in[l][n][k]; values identical, only layout changes.
__global__ void k_pack4(const float* __restrict__ in, float* __restrict__ out,
                        int N, int K, int total){
  int tid = blockIdx.x * blockDim.x + threadIdx.x;
  if (tid >= total) return;
  int S = N * K;
  int l = tid / S, r = tid - l*S;
  int k4g = r / (4*N);
  int r2 = r - k4g*4*N;
  int n = r2 >> 2, ku = r2 & 3;
  out[tid] = in[(size_t)l*S + (size_t)n*K + k4g*4 + ku];
}

// ---------------- persistent decode kernel ----------------
struct KParams {
  const float *emb, *sab, *sob, *f1b, *f2b;
  const float *g1,*b1,*g2,*b2,*g3,*b3,*fg,*fb;
  const float *o1b,*o2b,*o3w,*o3b;
  const float *cosb,*sinb,*cac;
  const float *sawP,*sowP,*f1wP,*f2wP,*o1wP,*o2wP;   // k4-packed weights [K/4][N][4]
  float *kc,*vc,*xl,*qb,*at,*ao,*x2,*fo,*h1,*xf,*hh1,*hh2,*ps3;
  int *pred;
  unsigned *bar;
};

__global__ __launch_bounds__(NTHR) void k_persist(KParams P){
  const int bid = blockIdx.x, tid = threadIdx.x;
  const int g = bid & 7;          // group (XCD-aligned under %8 round-robin; perf hint only)
  const int m = bid >> 3;         // member 0..31
  const int wid = tid >> 6, lane = tid & 63;
  __shared__ __align__(16) float smem[8704];

  for (int t = 1; t < TT; ++t){
    const int pp = t - 1;

    for (int l = 0; l < LL; ++l){
      // ================= S1: build x_l + QKV (24 blocks n-sliced) =================
      {
        float* sx   = smem;          // [4][512]
        float* part = smem + 2048;   // [8][4][64]
        float* srow = smem + 4096;   // [4][2]
        const int j = tid >> 7, d4 = (tid & 127) * 4;
        const int rb = g*4 + j;
        if (l == 0){
          int tok = P.pred[rb*TT + pp];
          #pragma unroll
          for (int e = d4; e < d4 + 4; e += 2){
            int i = e >> 1;
            float c = P.cosb[pp*256 + i], s = P.sinb[pp*256 + i];
            float e0 = P.emb[(size_t)tok*DD + e];
            float e1 = P.emb[(size_t)tok*DD + e + 1];
            sx[j*512 + e]     = fmaf(e0, c, -(e1*s));
            sx[j*512 + e + 1] = fmaf(e1, c, e0*s);
          }
        } else {
          if (tid < 4){
            float a = 0.f, bq = 0.f;
            const float* pr = P.ps3 + (size_t)(g*4 + tid)*64;
            for (int s = 0; s < 32; ++s){ a += pr[s*2]; bq += pr[s*2+1]; }
            float mu = a * (1.0f/512.0f);
            float var = bq * (1.0f/512.0f) - mu*mu;
            srow[tid*2]   = mu;
            srow[tid*2+1] = 1.0f / sqrtf(var + 1e-5f);
          }
          __syncthreads();
          float mu = srow[j*2], rs = srow[j*2+1];
          float4 xv = *(const float4*)&P.x2[(size_t)rb*DD + d4];
          float4 fv = *(const float4*)&P.fo[(size_t)rb*DD + d4];
          const float* g3r = P.g3 + (size_t)(l-1)*DD;
          const float* b3r = P.b3 + (size_t)(l-1)*DD;
          float yv[4] = {xv.x+fv.x, xv.y+fv.y, xv.z+fv.z, xv.w+fv.w};
          #pragma unroll
          for (int i = 0; i < 4; ++i)
            sx[j*512 + d4 + i] = (yv[i]-mu)*rs*g3r[d4+i] + b3r[d4+i];
        }
        __syncthreads();
        if (m == 0){   // materialize x_l
          float4 v = *(float4*)&sx[j*512 + d4];
          *(float4*)&P.xl[(size_t)rb*DD + d4] = v;
        }
        if (m < 24){
          const int n0 = m*64;
          // packed: float4 at (k4g*1536 + n), layer stride 512*1536/4 float4s
          const float4* wq = (const float4*)P.sawP + (size_t)l*(512/4)*1536
                           + (size_t)(wid*16)*1536 + n0 + lane;
          float a0=0.f,a1=0.f,a2=0.f,a3=0.f;
          #pragma unroll
          for (int k4 = 0; k4 < 16; ++k4){
            float4 w = wq[(size_t)k4*1536];
            const int kb = wid*64 + k4*4;
            float4 xa = *(const float4*)&sx[0*512 + kb];
            float4 xb = *(const float4*)&sx[1*512 + kb];
            float4 xc = *(const float4*)&sx[2*512 + kb];
            float4 xd = *(const float4*)&sx[3*512 + kb];
            a0=fmaf(w.x,xa.x,a0); a0=fmaf(w.y,xa.y,a0); a0=fmaf(w.z,xa.z,a0); a0=fmaf(w.w,xa.w,a0);
            a1=fmaf(w.x,xb.x,a1); a1=fmaf(w.y,xb.y,a1); a1=fmaf(w.z,xb.z,a1); a1=fmaf(w.w,xb.w,a1);
            a2=fmaf(w.x,xc.x,a2); a2=fmaf(w.y,xc.y,a2); a2=fmaf(w.z,xc.z,a2); a2=fmaf(w.w,xc.w,a2);
            a3=fmaf(w.x,xd.x,a3); a3=fmaf(w.y,xd.y,a3); a3=fmaf(w.z,xd.z,a3); a3=fmaf(w.w,xd.w,a3);
          }
          part[(wid*4+0)*64 + lane] = a0;
          part[(wid*4+1)*64 + lane] = a1;
          part[(wid*4+2)*64 + lane] = a2;
          part[(wid*4+3)*64 + lane] = a3;
          __syncthreads();
          if (tid < 256){
            int jr = tid >> 6, nl = tid & 63;
            int n = n0 + nl, rb2 = g*4 + jr;
            float s = P.sab[l*1536 + n];
            #pragma unroll
            for (int w = 0; w < 8; ++w) s += part[(w*4+jr)*64 + nl];
            if (n < DD){
              P.qb[(size_t)rb2*DD + n] = s;
            } else if (n < 2*DD){
              int h = (n - DD) >> 6, hd = (n - DD) & 63;
              P.kc[((((size_t)l*BB + rb2)*HH + h)*TT + pp)*HDIM + hd] = s;
            } else {
              int h = (n - 2*DD) >> 6, hd = (n - 2*DD) & 63;
              P.vc[((((size_t)l*BB + rb2)*HH + h)*TT + pp)*HDIM + hd] = s;
            }
          }
        }
      }
      gbar(P.bar, g);

      // ================= S2: attention (32 blocks = (row,head), 1 wave) =================
      {
        int bl = m >> 3, h = m & 7, rb = g*4 + bl;
        float* qs = smem; float* ps = smem + 64;
        if (tid < 64) qs[tid] = P.qb[(size_t)rb*DD + h*HDIM + tid];
        __syncthreads();
        if (tid < 64){
          const float* kb = P.kc + (((size_t)l*BB + rb)*HH + h)*TT*HDIM;
          float s = -INFINITY;
          if (lane <= pp && P.pred[rb*TT + lane] != 0){
            const float* kr = kb + lane*HDIM;
            float acc = 0.f;
            #pragma unroll
            for (int k2 = 0; k2 < HDIM; ++k2) acc = fmaf(qs[k2], kr[k2], acc);
            s = acc * 0.125f;
          }
          float mx = s;
          #pragma unroll
          for (int off = 32; off; off >>= 1) mx = fmaxf(mx, __shfl_xor(mx, off));
          float e = (s == -INFINITY) ? 0.f : expf(s - mx);
          float sum = e;
          #pragma unroll
          for (int off = 32; off; off >>= 1) sum += __shfl_xor(sum, off);
          ps[lane] = e / sum;
          const float* vb = P.vc + (((size_t)l*BB + rb)*HH + h)*TT*HDIM;
          float o = 0.f;
          int jj = 0;
          for (; jj + 8 <= t; jj += 8){
            float vv[8];
            #pragma unroll
            for (int u = 0; u < 8; ++u) vv[u] = vb[(jj+u)*HDIM + lane];
            #pragma unroll
            for (int u = 0; u < 8; ++u) o = fmaf(ps[jj+u], vv[u], o);
          }
          for (; jj <= pp; ++jj) o = fmaf(ps[jj], vb[jj*HDIM + lane], o);
          P.at[(size_t)rb*DD + h*HDIM + lane] = o;
        }
      }
      gbar(P.bar, g);

      // ================= S3: oproj (32 blocks, 16 cols each) =================
      {
        float* ats  = smem;          // [4][512]
        float* part = smem + 2048;   // [8][64]
        const int j = tid >> 7, d4 = (tid & 127) * 4;
        *(float4*)&ats[j*512 + d4] = *(const float4*)&P.at[(size_t)(g*4+j)*DD + d4];
        __syncthreads();
        const int n0 = m*16;
        const int jb = lane >> 4, nc = lane & 15;
        const float4* wq = (const float4*)P.sowP + (size_t)l*(512/4)*512
                         + (size_t)(wid*16)*512 + n0 + nc;
        float acc = 0.f;
        #pragma unroll
        for (int k4 = 0; k4 < 16; ++k4){
          float4 w = wq[(size_t)k4*512];
          const int kb = wid*64 + k4*4;
          float4 xa = *(const float4*)&ats[jb*512 + kb];
          acc=fmaf(w.x,xa.x,acc); acc=fmaf(w.y,xa.y,acc); acc=fmaf(w.z,xa.z,acc); acc=fmaf(w.w,xa.w,acc);
        }
        part[wid*64 + lane] = acc;
        __syncthreads();
        if (tid < 64){
          int jb2 = tid >> 4, nc2 = tid & 15, n = n0 + nc2;
          float s = P.sob[l*DD + n];
          #pragma unroll
          for (int w = 0; w < 8; ++w) s += part[w*64 + jb2*16 + nc2];
          P.ao[(size_t)(g*4+jb2)*DD + n] = s;
        }
      }
      gbar(P.bar, g);

      // ================= S4: ln1+ln2 (redundant) + FF1 (32 blocks, 64 cols) =================
      {
        float* sx2  = smem;          // [4][512]
        float* part = smem + 2048;   // [8][4][64]
        float* wred = smem + 4096;   // [8]
        const int j = tid >> 7, d4 = (tid & 127) * 4;
        const int rb = g*4 + j;
        float4 xlv = *(const float4*)&P.xl[(size_t)rb*DD + d4];
        float4 aov = *(const float4*)&P.ao[(size_t)rb*DD + d4];
        float y[4] = {xlv.x+aov.x, xlv.y+aov.y, xlv.z+aov.z, xlv.w+aov.w};
        float s = ((y[0]+y[1])+y[2])+y[3];
        float mu = row_reduce(s, wid, j, wred) * (1.0f/512.0f);
        float dv[4], sq = 0.f;
        #pragma unroll
        for (int i = 0; i < 4; ++i){ dv[i] = y[i]-mu; sq += dv[i]*dv[i]; }
        float rs = 1.0f / sqrtf(row_reduce(sq, wid, j, wred) * (1.0f/512.0f) + 1e-5f);
        float z[4];
        #pragma unroll
        for (int i = 0; i < 4; ++i){
          int d = d4 + i;
          z[i] = dv[i]*rs*P.g1[l*DD+d] + P.b1[l*DD+d] + P.cac[((size_t)l*BB + rb)*DD + d];
        }
        float s2 = ((z[0]+z[1])+z[2])+z[3];
        float mu2 = row_reduce(s2, wid, j, wred) * (1.0f/512.0f);
        float dz[4], sq2 = 0.f;
        #pragma unroll
        for (int i = 0; i < 4; ++i){ dz[i] = z[i]-mu2; sq2 += dz[i]*dz[i]; }
        float rs2 = 1.0f / sqrtf(row_reduce(sq2, wid, j, wred) * (1.0f/512.0f) + 1e-5f);
        float x2v[4];
        #pragma unroll
        for (int i = 0; i < 4; ++i){
          int d = d4 + i;
          x2v[i] = dz[i]*rs2*P.g2[l*DD+d] + P.b2[l*DD+d];
          sx2[j*512 + d] = x2v[i];
        }
        if (m == 0) *(float4*)&P.x2[(size_t)rb*DD + d4] = make_float4(x2v[0],x2v[1],x2v[2],x2v[3]);
        __syncthreads();
        // ff1 dot (packed float4 weights)
        const int n0 = m*64;
        const float4* wq = (const float4*)P.f1wP + (size_t)l*(512/4)*2048
                         + (size_t)(wid*16)*2048 + n0 + lane;
        float a0=0.f,a1=0.f,a2=0.f,a3=0.f;
        #pragma unroll
        for (int k4 = 0; k4 < 16; ++k4){
          float4 w = wq[(size_t)k4*2048];
          const int kb = wid*64 + k4*4;
          float4 xa = *(const float4*)&sx2[0*512 + kb];
          float4 xb = *(const float4*)&sx2[1*512 + kb];
          float4 xc = *(const float4*)&sx2[2*512 + kb];
          float4 xd = *(const float4*)&sx2[3*512 + kb];
          a0=fmaf(w.x,xa.x,a0); a0=fmaf(w.y,xa.y,a0); a0=fmaf(w.z,xa.z,a0); a0=fmaf(w.w,xa.w,a0);
          a1=fmaf(w.x,xb.x,a1); a1=fmaf(w.y,xb.y,a1); a1=fmaf(w.z,xb.z,a1); a1=fmaf(w.w,xb.w,a1);
          a2=fmaf(w.x,xc.x,a2); a2=fmaf(w.y,xc.y,a2); a2=fmaf(w.z,xc.z,a2); a2=fmaf(w.w,xc.w,a2);
          a3=fmaf(w.x,xd.x,a3); a3=fmaf(w.y,xd.y,a3); a3=fmaf(w.z,xd.z,a3); a3=fmaf(w.w,xd.w,a3);
        }
        part[(wid*4+0)*64 + lane] = a0;
        part[(wid*4+1)*64 + lane] = a1;
        part[(wid*4+2)*64 + lane] = a2;
        part[(wid*4+3)*64 + lane] = a3;
        __syncthreads();
        if (tid < 256){
          int jr = tid >> 6, nl = tid & 63;
          int n = n0 + nl;
          float v = P.f1b[l*FFD + n];
          #pragma unroll
          for (int w = 0; w < 8; ++w) v += part[(w*4+jr)*64 + nl];
          P.h1[(size_t)(g*4+jr)*FFD + n] = v / (1.0f + expf(-v));
        }
      }
      gbar(P.bar, g);

      // ================= S5: FF2 (32 blocks, 16 cols) + ln3 partials =================
      {
        float* sh1  = smem;          // [4][2048]
        float* part = smem + 8192;   // [8][64]
        #pragma unroll
        for (int q = 0; q < 4; ++q){
          int fi = tid + q*512;               // float4 index over [4][512]
          int j = fi >> 9, c4 = fi & 511;
          *(float4*)&sh1[j*2048 + c4*4] = *(const float4*)&P.h1[(size_t)(g*4+j)*FFD + c4*4];
        }
        __syncthreads();
        const int n0 = m*16;
        const int jb = lane >> 4, nc = lane & 15;
        const float4* wq = (const float4*)P.f2wP + (size_t)l*(2048/4)*512
                         + (size_t)(wid*64)*512 + n0 + nc;
        float acc = 0.f;
        #pragma unroll 16
        for (int k4 = 0; k4 < 64; ++k4){
          float4 w = wq[(size_t)k4*512];
          const int kb = wid*256 + k4*4;
          float4 xa = *(const float4*)&sh1[jb*2048 + kb];
          acc=fmaf(w.x,xa.x,acc); acc=fmaf(w.y,xa.y,acc); acc=fmaf(w.z,xa.z,acc); acc=fmaf(w.w,xa.w,acc);
        }
        part[wid*64 + lane] = acc;
        __syncthreads();
        if (tid < 64){
          int jb2 = tid >> 4, nc2 = tid & 15, n = n0 + nc2;
          int rb2 = g*4 + jb2;
          float val = P.f2b[l*DD + n];
          #pragma unroll
          for (int w = 0; w < 8; ++w) val += part[w*64 + jb2*16 + nc2];
          P.fo[(size_t)rb2*DD + n] = val;
          float y = P.x2[(size_t)rb2*DD + n] + val;
          float s1 = y, sq = y*y;
          #pragma unroll
          for (int off = 1; off < 16; off <<= 1){
            s1 += __shfl_xor(s1, off);
            sq += __shfl_xor(sq, off);
          }
          if (nc2 == 0){
            P.ps3[(size_t)(rb2*32 + m)*2]     = s1;
            P.ps3[(size_t)(rb2*32 + m)*2 + 1] = sq;
          }
        }
      }
      gbar(P.bar, g);
    }

    // ================= S6: final ln3 + fn ln (4 row blocks) =================
    if (m < 4){
      int rb = g*4 + m, d = tid;
      float y = P.x2[(size_t)rb*DD + d] + P.fo[(size_t)rb*DD + d];
      float xv = block_ln(y, P.g3[3*DD + d], P.b3[3*DD + d], smem);
      float o  = block_ln(xv, P.fg[d], P.fb[d], smem);
      P.xf[(size_t)rb*DD + d] = o;
    }
    gbar(P.bar, g);

    // ================= S7: head1 (32 blocks, 32 cols) =================
    {
      float* sxf  = smem;          // [4][512]
      float* part = smem + 2048;   // [8][2][64]
      const int j = tid >> 7, d4 = (tid & 127) * 4;
      *(float4*)&sxf[j*512 + d4] = *(const float4*)&P.xf[(size_t)(g*4+j)*DD + d4];
      __syncthreads();
      const int n0 = m*32;
      const int jh = lane >> 5, nc = lane & 31;
      const float4* wq = (const float4*)P.o1wP + (size_t)(wid*16)*1024 + n0 + nc;
      float ac0 = 0.f, ac1 = 0.f;
      #pragma unroll
      for (int k4 = 0; k4 < 16; ++k4){
        float4 w = wq[(size_t)k4*1024];
        const int kb = wid*64 + k4*4;
        float4 xa = *(const float4*)&sxf[jh*512 + kb];
        float4 xb = *(const float4*)&sxf[(jh+2)*512 + kb];
        ac0=fmaf(w.x,xa.x,ac0); ac0=fmaf(w.y,xa.y,ac0); ac0=fmaf(w.z,xa.z,ac0); ac0=fmaf(w.w,xa.w,ac0);
        ac1=fmaf(w.x,xb.x,ac1); ac1=fmaf(w.y,xb.y,ac1); ac1=fmaf(w.z,xb.z,ac1); ac1=fmaf(w.w,xb.w,ac1);
      }
      part[(wid*2+0)*64 + lane] = ac0;
      part[(wid*2+1)*64 + lane] = ac1;
      __syncthreads();
      if (tid < 128){
        int row = tid >> 5, nc2 = tid & 31;
        int r = row >> 1, jh2 = row & 1;
        float s = P.o1b[n0 + nc2];
        #pragma unroll
        for (int w = 0; w < 8; ++w) s += part[(w*2+r)*64 + jh2*32 + nc2];
        float a = s;
        P.hh1[(size_t)(g*4+row)*1024 + n0 + nc2] = 0.5f * a * (1.0f + erff(a / 1.41421356237309504880f));
      }
    }
    gbar(P.bar, g);

    // ================= S8: head2 (32 blocks, 32 cols, K=1024) =================
    {
      float* sh   = smem;          // [4][1024]
      float* part = smem + 4096;   // [8][2][64]
      #pragma unroll
      for (int q = 0; q < 2; ++q){
        int fi = tid + q*512;               // float4 index over [4][256]
        int j = fi >> 8, c4 = fi & 255;
        *(float4*)&sh[j*1024 + c4*4] = *(const float4*)&P.hh1[(size_t)(g*4+j)*1024 + c4*4];
      }
      __syncthreads();
      const int n0 = m*32;
      const int jh = lane >> 5, nc = lane & 31;
      const float4* wq = (const float4*)P.o2wP + (size_t)(wid*32)*1024 + n0 + nc;
      float ac0 = 0.f, ac1 = 0.f;
      #pragma unroll 16
      for (int k4 = 0; k4 < 32; ++k4){
        float4 w = wq[(size_t)k4*1024];
        const int kb = wid*128 + k4*4;
        float4 xa = *(const float4*)&sh[jh*1024 + kb];
        float4 xb = *(const float4*)&sh[(jh+2)*1024 + kb];
        ac0=fmaf(w.x,xa.x,ac0); ac0=fmaf(w.y,xa.y,ac0); ac0=fmaf(w.z,xa.z,ac0); ac0=fmaf(w.w,xa.w,ac0);
        ac1=fmaf(w.x,xb.x,ac1); ac1=fmaf(w.y,xb.y,ac1); ac1=fmaf(w.z,xb.z,ac1); ac1=fmaf(w.w,xb.w,ac1);
      }
      part[(wid*2+0)*64 + lane] = ac0;
      part[(wid*2+1)*64 + lane] = ac1;
      __syncthreads();
      if (tid < 128){
        int row = tid >> 5, nc2 = tid & 31;
        int r = row >> 1, jh2 = row & 1;
        float s = P.o2b[n0 + nc2];
        #pragma unroll
        for (int w = 0; w < 8; ++w) s += part[(w*2+r)*64 + jh2*32 + nc2];
        float a = s;
        P.hh2[(size_t)(g*4+row)*1024 + n0 + nc2] = 0.5f * a * (1.0f + erff(a / 1.41421356237309504880f));
      }
    }
    gbar(P.bar, g);

    // ================= S9: sample (4 row blocks; exact round-3 math) =================
    if (m < 4){
      int rb = g*4 + m, v = tid;
      float* hrow = smem;                 // 1024
      float* red  = smem + 1024;          // 8
      int*   redi = (int*)(smem + 1032);  // 2
      for (int k = tid; k < 1024; k += NTHR) hrow[k] = P.hh2[(size_t)rb*1024 + k];
      __syncthreads();
      float sv = 0.f;
      if (tid < 128){
        float acc = P.o3b[v] + dot_f4(hrow, P.o3w + (size_t)v*1024, 1024);
        sv = acc / 0.1f;
      }
      float mx = (tid < 128) ? sv : -INFINITY;
      #pragma unroll
      for (int off = 32; off; off >>= 1) mx = fmaxf(mx, __shfl_xor(mx, off));
      __syncthreads();
      if (tid < 128 && (tid & 63) == 0) red[tid >> 6] = mx;
      __syncthreads();
      mx = fmaxf(red[0], red[1]);
      float e = (tid < 128) ? expf(sv - mx) : 0.f;
      float sum = e;
      #pragma unroll
      for (int off = 32; off; off >>= 1) sum += __shfl_xor(sum, off);
      __syncthreads();
      if (tid < 128 && (tid & 63) == 0) red[tid >> 6] = sum;
      __syncthreads();
      sum = red[0] + red[1];
      float bv = -INFINITY; int bi = 0x7fffffff;
      if (tid < 128){
        float lp = (sv - mx) - logf(sum);
        uint32_t kk0, kk1, o0, o1;
        tf2x32(0u, 1u, 0u, (uint32_t)t, &kk0, &kk1);
        tf2x32(kk0, kk1, 0u, (uint32_t)(rb*VV + v), &o0, &o1);
        uint32_t bits = o0 ^ o1;
        float u = __uint_as_float((bits >> 9) | 0x3F800000u) - 1.0f;
        float gg = -logf(-logf(u + 1e-9f) + 1e-9f);
        bv = lp + gg; bi = v;
      }
      #pragma unroll
      for (int off = 32; off; off >>= 1){
        float ov = __shfl_xor(bv, off);
        int   oi = __shfl_xor(bi, off);
        if (ov > bv || (ov == bv && oi < bi)){ bv = ov; bi = oi; }
      }
      __syncthreads();
      if (tid < 128 && (tid & 63) == 0){ red[tid >> 6] = bv; redi[tid >> 6] = bi; }
      __syncthreads();
      if (tid == 0){
        float v0 = red[0], v1 = red[1]; int i0 = redi[0], i1 = redi[1];
        P.pred[rb*TT + t] = (v1 > v0 || (v1 == v0 && i1 < i0)) ? i1 : i0;
      }
    }
    gbar(P.bar, g);
  }
}

// ---------------- host ----------------
extern "C" void kernel_launch(void* const* d_in, const int* in_sizes, int n_in,
                              void* d_out, int out_size, void* d_ws, size_t ws_size,
                              hipStream_t stream){
  (void)in_sizes; (void)n_in; (void)out_size; (void)ws_size;
  const float* mol      = (const float*)d_in[1];
  const float* sa_in_w  = (const float*)d_in[3];
  const float* sa_out_w = (const float*)d_in[5];
  const float* ca_in_w  = (const float*)d_in[7];
  const float* ca_in_b  = (const float*)d_in[8];
  const float* ca_out_w = (const float*)d_in[9];
  const float* ca_out_b = (const float*)d_in[10];
  const float* ff_w1    = (const float*)d_in[11];
  const float* ff_w2    = (const float*)d_in[13];
  const float* out_w1   = (const float*)d_in[23];
  const float* out_w2   = (const float*)d_in[25];

  KParams P;
  P.emb = (const float*)d_in[2];
  P.sab = (const float*)d_in[4];
  P.sob = (const float*)d_in[6];
  P.f1b = (const float*)d_in[12];
  P.f2b = (const float*)d_in[14];
  P.g1  = (const float*)d_in[15];
  P.b1  = (const float*)d_in[16];
  P.g2  = (const float*)d_in[17];
  P.b2  = (const float*)d_in[18];
  P.g3  = (const float*)d_in[19];
  P.b3  = (const float*)d_in[20];
  P.fg  = (const float*)d_in[21];
  P.fb  = (const float*)d_in[22];
  P.o1b = (const float*)d_in[24];
  P.o2b = (const float*)d_in[26];
  P.o3w = (const float*)d_in[27];
  P.o3b = (const float*)d_in[28];

  unsigned* bar = (unsigned*)d_ws;          // 1024 uints
  float* ws = (float*)d_ws + 1024;
  float* cosb   = ws;                       // 16384
  float* sinb   = cosb + 16384;             // 16384
  float* ca_tmp = sinb + 16384;             // 65536
  float* cac    = ca_tmp + 65536;           // 65536
  float* kc     = cac + 65536;              // 4194304
  float* vc     = kc + 4194304;             // 4194304
  float* xl     = vc + 4194304;             // 16384
  float* qb     = xl + 16384;               // 16384
  float* at     = qb + 16384;               // 16384
  float* ao     = at + 16384;               // 16384
  float* x2     = ao + 16384;               // 16384
  float* fo     = x2 + 16384;               // 16384
  float* h1     = fo + 16384;               // 65536
  float* xf     = h1 + 65536;               // 16384
  float* hh1    = xf + 16384;               // 32768
  float* hh2    = hh1 + 32768;              // 32768
  float* ps3    = hh2 + 32768;              // 2048
  float* sawP   = ps3 + 2048;               // 3145728
  float* sowP   = sawP + 3145728;           // 1048576
  float* f1wP   = sowP + 1048576;           // 4194304
  float* f2wP   = f1wP + 4194304;           // 4194304
  float* o1wP   = f2wP + 4194304;           // 524288
  float* o2wP   = o1wP + 524288;            // 1048576

  P.cosb = cosb; P.sinb = sinb; P.cac = cac;
  P.kc = kc; P.vc = vc; P.xl = xl; P.qb = qb; P.at = at; P.ao = ao;
  P.x2 = x2; P.fo = fo; P.h1 = h1; P.xf = xf; P.hh1 = hh1; P.hh2 = hh2;
  P.ps3 = ps3;
  P.sawP = sawP; P.sowP = sowP; P.f1wP = f1wP; P.f2wP = f2wP;
  P.o1wP = o1wP; P.o2wP = o2wP;
  P.pred = (int*)d_out;
  P.bar = bar;

  k_binit<<<1, 1024, 0, stream>>>(bar, P.pred);
  k_tables<<<64, 256, 0, stream>>>(cosb, sinb);
  k_ca1<<<256, 256, 0, stream>>>(mol, ca_in_w, ca_in_b, ca_tmp);
  k_ca2<<<256, 256, 0, stream>>>(ca_tmp, ca_out_w, ca_out_b, cac);

  // k4-pack all streamed weights: [L][N][K] -> [L][K/4][N][4]
  {
    int t1 = 4*1536*512;  k_pack4<<<(t1+255)/256, 256, 0, stream>>>(sa_in_w,  sawP, 1536, 512,  t1);
    int t2 = 4*512*512;   k_pack4<<<(t2+255)/256, 256, 0, stream>>>(sa_out_w, sowP,  512, 512,  t2);
    int t3 = 4*2048*512;  k_pack4<<<(t3+255)/256, 256, 0, stream>>>(ff_w1,    f1wP, 2048, 512,  t3);
    int t4 = 4*512*2048;  k_pack4<<<(t4+255)/256, 256, 0, stream>>>(ff_w2,    f2wP,  512, 2048, t4);
    int t5 = 1024*512;    k_pack4<<<(t5+255)/256, 256, 0, stream>>>(out_w1,   o1wP, 1024, 512,  t5);
    int t6 = 1024*1024;   k_pack4<<<(t6+255)/256, 256, 0, stream>>>(out_w2,   o2wP, 1024, 1024, t6);
  }

  k_persist<<<NBLK, NTHR, 0, stream>>>(P);
}